// Round 9
// baseline (344.448 us; speedup 1.0000x reference)
//
#include <hip/hip_runtime.h>

#define EPS 1e-5f

typedef __bf16 bf16x8 __attribute__((ext_vector_type(8)));
typedef __bf16 bf16x4 __attribute__((ext_vector_type(4)));
typedef float f32x4 __attribute__((ext_vector_type(4)));

static __device__ __forceinline__ unsigned int f2bf(float f) {
    unsigned int u = __builtin_bit_cast(unsigned int, f);
    u = (u + 0x7fffu + ((u >> 16) & 1u)) >> 16;
    return u;
}
static __device__ __forceinline__ float bf2f(unsigned int lo16) {
    unsigned int u = lo16 << 16;
    return __builtin_bit_cast(float, u);
}

// async global->LDS, 16B per lane. LDS dest is wave-uniform base (+lane*16 by HW).
static __device__ __forceinline__ void gll16(const void* g, void* l) {
    __builtin_amdgcn_global_load_lds(
        (const __attribute__((address_space(1))) unsigned int*)(unsigned long long)g,
        (__attribute__((address_space(3))) unsigned int*)(unsigned int)(unsigned long long)l,
        16, 0, 0);
}

// ---- pass 1: colsum partials (+ optional bf16 copy of x) ----
template <int XBF>
__global__ __launch_bounds__(256) void k_prep(const float* __restrict__ x,
                                              float* __restrict__ xs_part,
                                              unsigned short* __restrict__ xbf) {
    const int b = blockIdx.y, sc = blockIdx.x, tid = threadIdx.x;
    const size_t rowbase = ((size_t)(b * 4096 + sc * 128)) * 1024;
    const float4* src = (const float4*)(x + rowbase) + tid;
    uint2* dst = XBF ? ((uint2*)(xbf + rowbase) + tid) : (uint2*)0;
    float ax = 0.f, ay = 0.f, az = 0.f, aw = 0.f;
    for (int r = 0; r < 128; ++r) {
        float4 v = src[r * 256];
        ax += v.x; ay += v.y; az += v.z; aw += v.w;
        if (XBF) {
            uint2 p;
            p.x = f2bf(v.x) | (f2bf(v.y) << 16);
            p.y = f2bf(v.z) | (f2bf(v.w) << 16);
            dst[r * 256] = p;
        }
    }
    float4 o; o.x = ax; o.y = ay; o.z = az; o.w = aw;
    ((float4*)(xs_part + ((size_t)(b * 32 + sc)) * 1024))[tid] = o;
}

// ---- merged: B->bf16 convert (blocks 0..1023) + xsred+query (blocks 1024..1087) ----
__global__ __launch_bounds__(256) void k_glue(const float* __restrict__ B,
                                              unsigned short* __restrict__ Bb,
                                              const float* __restrict__ xs_part,
                                              const float* __restrict__ A,
                                              float* __restrict__ q) {
    __shared__ float xsl[1024];
    const int blk = blockIdx.x, tid = threadIdx.x;
    if (blk < 1024) {
        const int i = blk * 256 + tid;
        float4 v = ((const float4*)B)[i];
        uint2 p;
        p.x = f2bf(v.x) | (f2bf(v.y) << 16);
        p.y = f2bf(v.z) | (f2bf(v.w) << 16);
        ((uint2*)Bb)[i] = p;
        return;
    }
    const int gb = blk - 1024;
    const int g = gb & 3, b = gb >> 2;
    {
        float4 s4 = {0.f, 0.f, 0.f, 0.f};
        const float4* p = (const float4*)(xs_part + (size_t)b * 32768) + tid;
        for (int sc = 0; sc < 32; ++sc) {
            float4 v = p[sc * 256];
            s4.x += v.x; s4.y += v.y; s4.z += v.z; s4.w += v.w;
        }
        ((float4*)xsl)[tid] = s4;
    }
    __syncthreads();
    const int i = g * 256 + tid;
    const float4* ar = (const float4*)(A + (size_t)i * 1024);
    float acc = 0.f;
    for (int k = 0; k < 256; ++k) {
        float4 a = ar[k], v = ((const float4*)xsl)[k];
        acc += a.x * v.x + a.y * v.y + a.z * v.z + a.w * v.w;
    }
    q[b * 1024 + i] = acc;
}

// ---- fused qnorm + w (row-major sweep): w[b,j] = sum_i B[i,j] * qhat[b,i] ----
// 16 blocks (one per batch); thread owns 4 j-columns; B rows read coalesced.
__global__ __launch_bounds__(256) void k_wf(const float* __restrict__ B,
                                            const float* __restrict__ q,
                                            float* __restrict__ w) {
    __shared__ float ql[1024];
    __shared__ float wsum[4];
    const int b = blockIdx.x, tid = threadIdx.x;
    float4 v = ((const float4*)(q + (size_t)b * 1024))[tid];
    float ss = v.x * v.x + v.y * v.y + v.z * v.z + v.w * v.w;
    for (int o = 1; o < 64; o <<= 1) ss += __shfl_xor(ss, o);
    if ((tid & 63) == 0) wsum[tid >> 6] = ss;
    __syncthreads();
    const float inv = 1.f / (EPS + sqrtf(wsum[0] + wsum[1] + wsum[2] + wsum[3]));
    float4 n; n.x = v.x * inv; n.y = v.y * inv; n.z = v.z * inv; n.w = v.w * inv;
    ((float4*)ql)[tid] = n;
    __syncthreads();
    float4 acc = {0.f, 0.f, 0.f, 0.f};
    const float4* Br = (const float4*)B + tid;  // row i: Br[i*256]
    for (int i = 0; i < 1024; ++i) {
        float4 br = Br[(size_t)i * 256];
        float qi = ql[i];
        acc.x += br.x * qi; acc.y += br.y * qi; acc.z += br.z * qi; acc.w += br.w * qi;
    }
    ((float4*)(w + (size_t)b * 1024))[tid] = acc;
}

#define FENCE asm volatile("" ::: "memory")

// ---- fused main: nsq GEMM + numer-in-shadow + direct out ----
// grid = 512 blocks (2/CU), 256 threads (4 waves 2x2; wave tile 64 tok x 64 m).
// Per block: 128 tokens x all 1024 m (8 m-tiles of 128), BK=64, dbuf LDS 64 KB,
// counted vmcnt(8) coarse schedule (r4-proven), 2 blocks/CU for stall overlap.
__global__ __launch_bounds__(256, 2) void k_main3(const unsigned short* __restrict__ xbf,
                                                  const unsigned short* __restrict__ Bb,
                                                  const float* __restrict__ w,
                                                  float* __restrict__ out,
                                                  float* __restrict__ sim_out) {
    __shared__ __align__(16) unsigned short Xs[2][128 * 64];  // 16 KB x2
    __shared__ __align__(16) unsigned short Bs[2][128 * 64];  // 16 KB x2
    __shared__ float nsq_s[128];
    __shared__ float numer_s[128];
    __shared__ float simv_s[128];
    __shared__ float wlds[1024];

    const int tid = threadIdx.x;
    const int lane = tid & 63;
    const int l15 = lane & 15, lg = lane >> 4;
    const int w4 = tid >> 6;
    const int wm = w4 >> 1, wn = w4 & 1;
    const int bx = blockIdx.x;
    const size_t tok0 = (size_t)bx * 128;
    const int b = bx >> 5;  // 32 blocks per batch

    ((float4*)wlds)[tid] = ((const float4*)(w + (size_t)b * 1024))[tid];
    if (tid < 128) nsq_s[tid] = 0.f;
    __syncthreads();  // init visible before any use

    // stage step s (mt=s>>4, ks=s&15): X 128x64 + B[mt] 128x64, 8 gll16/thread,
    // linear LDS dest, pre-swizzled source chunk c^(row&7).
#define STAGE(s_, buf_)                                                                  \
    do {                                                                                 \
        const int mt_ = (s_) >> 4, ks_ = (s_) & 15;                                      \
        _Pragma("unroll") for (int it = 0; it < 4; ++it) {                               \
            const int g_ = it * 256 + tid;                                               \
            const int row_ = g_ >> 3, c_ = g_ & 7;                                       \
            const int csw_ = (c_ ^ (row_ & 7)) * 8;                                      \
            gll16(xbf + (tok0 + row_) * 1024 + ks_ * 64 + csw_,                          \
                  (char*)Xs[buf_] + (size_t)(it * 256 + (tid & ~63)) * 16);              \
            gll16(Bb + (size_t)(mt_ * 128 + row_) * 1024 + ks_ * 64 + csw_,              \
                  (char*)Bs[buf_] + (size_t)(it * 256 + (tid & ~63)) * 16);              \
        }                                                                                \
    } while (0)

    f32x4 acc[4][4];
    float numer_acc = 0.f;
    const int ntok = tid >> 1, nhalf = tid & 1;  // numer: 2 threads per token
    const int nswt = (ntok & 7) << 4;

    STAGE(0, 0);
    STAGE(1, 1);

    for (int s = 0; s < 128; ++s) {
        const int buf = s & 1;
        if ((s & 15) == 0) {
#pragma unroll
            for (int mi = 0; mi < 4; ++mi)
#pragma unroll
                for (int ni = 0; ni < 4; ++ni) acc[mi][ni] = (f32x4){0.f, 0.f, 0.f, 0.f};
        }
        // leading sync: drain this step's 8 loads (next step's 8 stay in flight)
        if (s < 126) asm volatile("s_waitcnt vmcnt(8)" ::: "memory");
        else         asm volatile("s_waitcnt vmcnt(0)" ::: "memory");
        __builtin_amdgcn_s_barrier();

        const char* xb = (const char*)Xs[buf] + (wm * 64 + l15) * 128;
        const char* bb = (const char*)Bs[buf] + (wn * 64 + l15) * 128;
        const int sw = (l15 & 7) << 4;

        bf16x8 a[4][2], bq[4][2];
#pragma unroll
        for (int kk = 0; kk < 2; ++kk) {
            const int ob = (kk * 64 + lg * 16) ^ sw;
#pragma unroll
            for (int mi = 0; mi < 4; ++mi) a[mi][kk] = *(const bf16x8*)(xb + mi * 16 * 128 + ob);
#pragma unroll
            for (int ni = 0; ni < 4; ++ni) bq[ni][kk] = *(const bf16x8*)(bb + ni * 16 * 128 + ob);
        }

        __builtin_amdgcn_s_setprio(1);
#pragma unroll
        for (int kk = 0; kk < 2; ++kk)
#pragma unroll
            for (int mi = 0; mi < 4; ++mi)
#pragma unroll
                for (int ni = 0; ni < 4; ++ni)
                    acc[mi][ni] = __builtin_amdgcn_mfma_f32_16x16x32_bf16(
                        a[mi][kk], bq[ni][kk], acc[mi][ni], 0, 0, 0);
        __builtin_amdgcn_s_setprio(0);

        // numer (m-tile 0 only, s=0..15 == ks): dot X chunk with w in MFMA shadow.
        if (s < 16) {
            const char* pt = (const char*)Xs[buf] + ntok * 128;
            const float* wp = wlds + s * 64 + nhalf * 32;
            float na = 0.f;
#pragma unroll
            for (int j = 0; j < 4; ++j) {
                bf16x8 v = *(const bf16x8*)(pt + ((nhalf * 64 + j * 16) ^ nswt));
#pragma unroll
                for (int e = 0; e < 8; ++e) na += (float)v[e] * wp[j * 8 + e];
            }
            numer_acc += na;
        }

        FENCE;
        __builtin_amdgcn_s_barrier();  // all waves done reading buf; safe to overwrite
        FENCE;
        if (s + 2 < 128) STAGE(s + 2, buf);

        if ((s & 15) == 15) {  // end of m-tile: fold squares, reduce, LDS-atomic
#pragma unroll
            for (int mi = 0; mi < 4; ++mi)
#pragma unroll
                for (int r = 0; r < 4; ++r) {
                    float v = 0.f;
#pragma unroll
                    for (int ni = 0; ni < 4; ++ni) v += acc[mi][ni][r] * acc[mi][ni][r];
                    v += __shfl_xor(v, 1);
                    v += __shfl_xor(v, 2);
                    v += __shfl_xor(v, 4);
                    v += __shfl_xor(v, 8);
                    if (l15 == 0) atomicAdd(&nsq_s[wm * 64 + mi * 16 + lg * 4 + r], v);
                }
        }
        if (s == 15) {  // numer complete: pair-reduce into numer_s
            float na = numer_acc + __shfl_xor(numer_acc, 1);
            if (nhalf == 0) numer_s[ntok] = na;
        }
    }
#undef STAGE

    __syncthreads();  // nsq_s atomics + numer_s visible
    if (tid < 128) {
        float sv = numer_s[tid] / (EPS + sqrtf(nsq_s[tid]));
        simv_s[tid] = sv;
        sim_out[tok0 + tid] = sv;
    }
    __syncthreads();

    // out: each thread owns 4 columns; read xbf direct (L3-resident), atomicAdd.
    {
        const unsigned short* xp = xbf + tok0 * 1024 + tid * 4;
        float oa0 = 0.f, oa1 = 0.f, oa2 = 0.f, oa3 = 0.f;
#pragma unroll 8
        for (int t = 0; t < 128; ++t) {
            uint2 u = *(const uint2*)(xp + (size_t)t * 1024);
            float sv = simv_s[t];
            oa0 += sv * bf2f(u.x & 0xffffu);
            oa1 += sv * bf2f(u.x >> 16);
            oa2 += sv * bf2f(u.y & 0xffffu);
            oa3 += sv * bf2f(u.y >> 16);
        }
        float* dst = out + (size_t)b * 1024 + tid * 4;
        atomicAdd(dst + 0, oa0);
        atomicAdd(dst + 1, oa1);
        atomicAdd(dst + 2, oa2);
        atomicAdd(dst + 3, oa3);
    }
}

// ---- fallback pass 3 (no xbf workspace): 128x128 tile from f32 x ----
__global__ __launch_bounds__(256, 2) void k_nsq_f32(const float* __restrict__ x,
                                                    const unsigned short* __restrict__ Bb,
                                                    float* __restrict__ nsq_g) {
    __shared__ unsigned short Xs[128 * 64];
    __shared__ unsigned short Bs[128 * 64];
    __shared__ float nsq_s[128];

    const int tid = threadIdx.x;
    const int lane = tid & 63;
    const int l15 = lane & 15, lg = lane >> 4;
    const int w = tid >> 6;
    const int wr = w >> 1, wc = w & 1;
    const int st = blockIdx.x * 128;
    const int mh = blockIdx.y;

    float nsq_reg[4][4];
#pragma unroll
    for (int mi = 0; mi < 4; ++mi)
#pragma unroll
        for (int r = 0; r < 4; ++r) nsq_reg[mi][r] = 0.f;

    for (int mti = 0; mti < 4; ++mti) {
        const int mt = mh * 4 + mti;
        f32x4 acc[4][4];
#pragma unroll
        for (int mi = 0; mi < 4; ++mi)
#pragma unroll
            for (int ni = 0; ni < 4; ++ni) acc[mi][ni] = (f32x4){0.f, 0.f, 0.f, 0.f};

        for (int ks = 0; ks < 16; ++ks) {
            __syncthreads();
            {
                const int row = tid >> 1, kh = tid & 1;
                const float* srcx = x + (size_t)(st + row) * 1024 + ks * 64 + kh * 32;
                char* ldsrow = (char*)Xs + row * 128;
                const int sw = (row & 7) << 4;
#pragma unroll
                for (int j = 0; j < 4; ++j) {
                    float4 v0 = ((const float4*)srcx)[j * 2];
                    float4 v1 = ((const float4*)srcx)[j * 2 + 1];
                    uint4 p;
                    p.x = f2bf(v0.x) | (f2bf(v0.y) << 16);
                    p.y = f2bf(v0.z) | (f2bf(v0.w) << 16);
                    p.z = f2bf(v1.x) | (f2bf(v1.y) << 16);
                    p.w = f2bf(v1.z) | (f2bf(v1.w) << 16);
                    *(uint4*)(ldsrow + (((kh * 4 + j) * 16) ^ sw)) = p;
                }
#pragma unroll
                for (int it = 0; it < 4; ++it) {
                    const int idx = it * 256 + tid;
                    const int brow = idx >> 3, c = idx & 7;
                    char* baseB = (char*)Bs + (size_t)(it * 256 + (tid & ~63)) * 16;
                    gll16(Bb + (size_t)(mt * 128 + brow) * 1024 + ks * 64 + (c ^ (brow & 7)) * 8,
                          baseB);
                }
            }
            __syncthreads();

            const char* xb = (const char*)Xs + (wr * 64 + l15) * 128;
            const char* bb = (const char*)Bs + (wc * 64 + l15) * 128;
            const int sw = (l15 & 7) << 4;
#pragma unroll
            for (int kk = 0; kk < 2; ++kk) {
                const int ob = (kk * 64 + lg * 16) ^ sw;
                bf16x8 a[4], bq[4];
#pragma unroll
                for (int mi = 0; mi < 4; ++mi) a[mi] = *(const bf16x8*)(xb + mi * 2048 + ob);
#pragma unroll
                for (int ni = 0; ni < 4; ++ni) bq[ni] = *(const bf16x8*)(bb + ni * 2048 + ob);
#pragma unroll
                for (int mi = 0; mi < 4; ++mi)
#pragma unroll
                    for (int ni = 0; ni < 4; ++ni)
                        acc[mi][ni] = __builtin_amdgcn_mfma_f32_16x16x32_bf16(
                            a[mi], bq[ni], acc[mi][ni], 0, 0, 0);
            }
        }
#pragma unroll
        for (int mi = 0; mi < 4; ++mi)
#pragma unroll
            for (int ni = 0; ni < 4; ++ni)
#pragma unroll
                for (int r = 0; r < 4; ++r)
                    nsq_reg[mi][r] += acc[mi][ni][r] * acc[mi][ni][r];
    }

    if (tid < 128) nsq_s[tid] = 0.f;
    __syncthreads();
#pragma unroll
    for (int mi = 0; mi < 4; ++mi)
#pragma unroll
        for (int r = 0; r < 4; ++r) {
            float v = nsq_reg[mi][r];
            v += __shfl_xor(v, 1);
            v += __shfl_xor(v, 2);
            v += __shfl_xor(v, 4);
            v += __shfl_xor(v, 8);
            if (l15 == 0) atomicAdd(&nsq_s[wr * 64 + mi * 16 + lg * 4 + r], v);
        }
    __syncthreads();
    if (tid < 128) nsq_g[(size_t)mh * 65536 + st + tid] = nsq_s[tid];
}

// ---- fallback pass 4 ----
__global__ __launch_bounds__(256, 2) void k_finish0(
    const float* __restrict__ x, const float* __restrict__ w,
    const float* __restrict__ nsq_g, float* __restrict__ outp,
    float* __restrict__ sim_out) {
    __shared__ __align__(16) unsigned short xt[32 * 1024];
    __shared__ float numer[32];
    __shared__ float simv[32];

    const int tid = threadIdx.x;
    const int bs = blockIdx.x;
    const int b = bs >> 7, s0 = (bs & 127) * 32;
    const size_t tok0 = (size_t)b * 4096 + s0;

    const float4* src = (const float4*)(x + tok0 * 1024) + tid;
    char* lds = (char*)xt;
    for (int r = 0; r < 32; ++r) {
        float4 v = src[r * 256];
        uint2 p;
        p.x = f2bf(v.x) | (f2bf(v.y) << 16);
        p.y = f2bf(v.z) | (f2bf(v.w) << 16);
        *(uint2*)(lds + r * 2048 + ((tid * 8) ^ ((r & 7) << 4))) = p;
    }
    __syncthreads();

    {
        const int t = tid >> 3, kp = tid & 7;
        const float* wb = w + (size_t)b * 1024 + kp * 128;
        const char* pt = (const char*)xt + t * 2048;
        const int sw2 = (t & 7) << 4;
        float acc = 0.f;
#pragma unroll
        for (int j = 0; j < 16; ++j) {
            const int kb = (kp * 128 + j * 8) * 2;
            bf16x8 v = *(const bf16x8*)(pt + (kb ^ sw2));
#pragma unroll
            for (int e = 0; e < 8; ++e) acc += (float)v[e] * wb[j * 8 + e];
        }
        acc += __shfl_xor(acc, 1);
        acc += __shfl_xor(acc, 2);
        acc += __shfl_xor(acc, 4);
        if (kp == 0) numer[t] = acc;
    }
    __syncthreads();

    if (tid < 32) {
        float nt = nsq_g[tok0 + tid] + nsq_g[65536 + tok0 + tid];
        float s = numer[tid] / (EPS + sqrtf(nt));
        simv[tid] = s;
        sim_out[tok0 + tid] = s;
    }
    __syncthreads();

    {
        const int n0 = tid * 4;
        float a0 = 0.f, a1 = 0.f, a2 = 0.f, a3 = 0.f;
        const char* p = (const char*)xt;
#pragma unroll 4
        for (int t = 0; t < 32; ++t) {
            int byte = t * 2048 + ((n0 * 2) ^ ((t & 7) << 4));
            bf16x4 v = *(const bf16x4*)(p + byte);
            float s = simv[t];
            a0 += s * (float)v[0];
            a1 += s * (float)v[1];
            a2 += s * (float)v[2];
            a3 += s * (float)v[3];
        }
        float4 o; o.x = a0; o.y = a1; o.z = a2; o.w = a3;
        ((float4*)(outp + (size_t)bs * 1024))[tid] = o;
    }
}

// ---- out[b][j] = sum over NT tile partials (fallback) ----
template <int NT>
__global__ void k_outred(const float* __restrict__ outp, float* __restrict__ out) {
    const int b = blockIdx.y, j = blockIdx.x * 256 + threadIdx.x;
    const float* p = outp + (size_t)b * NT * 1024 + j;
    float s = 0.f;
    for (int t = 0; t < NT; ++t) s += p[t * 1024];
    out[b * 1024 + j] = s;
}

extern "C" void kernel_launch(void* const* d_in, const int* in_sizes, int n_in,
                              void* d_out, int out_size, void* d_ws, size_t ws_size,
                              hipStream_t stream) {
    const float* x = (const float*)d_in[0];  // [16][4096][1024]
    const float* A = (const float*)d_in[1];  // [1024][1024]
    const float* B = (const float*)d_in[2];  // [1024][1024]
    float* out = (float*)d_out;              // [16][1024] then sim [16][4096]
    float* sim = out + 16 * 1024;
    float* ws = (float*)d_ws;
    float* xs_part = ws;                                  // 524288  (2 MB)
    float* q = ws + 540672;                               // 16384
    float* wv = ws + 557056;                              // 16384
    float* nsq = ws + 573440;                             // 131072 (fallback only)
    float* outp = ws + 704512;                            // up to 8 MB (fallback only)
    unsigned short* Bb = (unsigned short*)(ws + 2801664); // 1M bf16 (2 MB)
    unsigned short* xbf = (unsigned short*)(ws + 3325952);// 64M bf16 (128 MB, optional)
    const bool xb = ws_size >= (size_t)(3325952 + 33554432) * 4;

    if (xb) {
        hipMemsetAsync(d_out, 0, 16 * 1024 * sizeof(float), stream);  // out accumulated atomically
        k_prep<1><<<dim3(32, 16), 256, 0, stream>>>(x, xs_part, xbf);
        k_glue<<<1088, 256, 0, stream>>>(B, Bb, xs_part, A, q);
        k_wf<<<16, 256, 0, stream>>>(B, q, wv);
        k_main3<<<512, 256, 0, stream>>>(xbf, Bb, wv, out, sim);
    } else {
        k_prep<0><<<dim3(32, 16), 256, 0, stream>>>(x, xs_part, (unsigned short*)0);
        k_glue<<<1088, 256, 0, stream>>>(B, Bb, xs_part, A, q);
        k_wf<<<16, 256, 0, stream>>>(B, q, wv);
        k_nsq_f32<<<dim3(512, 2), 256, 0, stream>>>(x, Bb, nsq);
        k_finish0<<<2048, 256, 0, stream>>>(x, wv, nsq, outp, sim);
        k_outred<128><<<dim3(4, 16), 256, 0, stream>>>(outp, out);
    }
}

// Round 10
// 325.720 us; speedup vs baseline: 1.0575x; 1.0575x over previous
//
#include <hip/hip_runtime.h>

#define EPS 1e-5f

typedef __bf16 bf16x8 __attribute__((ext_vector_type(8)));
typedef __bf16 bf16x4 __attribute__((ext_vector_type(4)));
typedef __bf16 bf16x2 __attribute__((ext_vector_type(2)));
typedef float f32x4 __attribute__((ext_vector_type(4)));

static __device__ __forceinline__ unsigned int f2bf(float f) {
    unsigned int u = __builtin_bit_cast(unsigned int, f);
    u = (u + 0x7fffu + ((u >> 16) & 1u)) >> 16;
    return u;
}

// async global->LDS, 16B per lane. LDS dest is wave-uniform base (+lane*16 by HW).
static __device__ __forceinline__ void gll16(const void* g, void* l) {
    __builtin_amdgcn_global_load_lds(
        (const __attribute__((address_space(1))) unsigned int*)(unsigned long long)g,
        (__attribute__((address_space(3))) unsigned int*)(unsigned int)(unsigned long long)l,
        16, 0, 0);
}

// ---- pass 1: colsum partials (+ optional bf16 copy of x) ----
template <int XBF>
__global__ __launch_bounds__(256) void k_prep(const float* __restrict__ x,
                                              float* __restrict__ xs_part,
                                              unsigned short* __restrict__ xbf) {
    const int b = blockIdx.y, sc = blockIdx.x, tid = threadIdx.x;
    const size_t rowbase = ((size_t)(b * 4096 + sc * 128)) * 1024;
    const float4* src = (const float4*)(x + rowbase) + tid;
    uint2* dst = XBF ? ((uint2*)(xbf + rowbase) + tid) : (uint2*)0;
    float ax = 0.f, ay = 0.f, az = 0.f, aw = 0.f;
    for (int r = 0; r < 128; ++r) {
        float4 v = src[r * 256];
        ax += v.x; ay += v.y; az += v.z; aw += v.w;
        if (XBF) {
            uint2 p;
            p.x = f2bf(v.x) | (f2bf(v.y) << 16);
            p.y = f2bf(v.z) | (f2bf(v.w) << 16);
            dst[r * 256] = p;
        }
    }
    float4 o; o.x = ax; o.y = ay; o.z = az; o.w = aw;
    ((float4*)(xs_part + ((size_t)(b * 32 + sc)) * 1024))[tid] = o;
}

// ---- merged: B->bf16 convert (blocks 0..1023) + xsred+query (blocks 1024..1087) ----
__global__ __launch_bounds__(256) void k_glue(const float* __restrict__ B,
                                              unsigned short* __restrict__ Bb,
                                              const float* __restrict__ xs_part,
                                              const float* __restrict__ A,
                                              float* __restrict__ q) {
    __shared__ float xsl[1024];
    const int blk = blockIdx.x, tid = threadIdx.x;
    if (blk < 1024) {
        const int i = blk * 256 + tid;
        float4 v = ((const float4*)B)[i];
        uint2 p;
        p.x = f2bf(v.x) | (f2bf(v.y) << 16);
        p.y = f2bf(v.z) | (f2bf(v.w) << 16);
        ((uint2*)Bb)[i] = p;
        return;
    }
    const int gb = blk - 1024;
    const int g = gb & 3, b = gb >> 2;
    {
        float4 s4 = {0.f, 0.f, 0.f, 0.f};
        const float4* p = (const float4*)(xs_part + (size_t)b * 32768) + tid;
        for (int sc = 0; sc < 32; ++sc) {
            float4 v = p[sc * 256];
            s4.x += v.x; s4.y += v.y; s4.z += v.z; s4.w += v.w;
        }
        ((float4*)xsl)[tid] = s4;
    }
    __syncthreads();
    const int i = g * 256 + tid;
    const float4* ar = (const float4*)(A + (size_t)i * 1024);
    float acc = 0.f;
    for (int k = 0; k < 256; ++k) {
        float4 a = ar[k], v = ((const float4*)xsl)[k];
        acc += a.x * v.x + a.y * v.y + a.z * v.z + a.w * v.w;
    }
    q[b * 1024 + i] = acc;
}

// ---- fused qnorm + w (row-major sweep): w[b,j] = sum_i B[i,j] * qhat[b,i] ----
// 16 blocks (one per batch); thread owns 4 j-columns; B rows read coalesced.
__global__ __launch_bounds__(256) void k_wf(const float* __restrict__ B,
                                            const float* __restrict__ q,
                                            float* __restrict__ w) {
    __shared__ float ql[1024];
    __shared__ float wsum[4];
    const int b = blockIdx.x, tid = threadIdx.x;
    float4 v = ((const float4*)(q + (size_t)b * 1024))[tid];
    float ss = v.x * v.x + v.y * v.y + v.z * v.z + v.w * v.w;
    for (int o = 1; o < 64; o <<= 1) ss += __shfl_xor(ss, o);
    if ((tid & 63) == 0) wsum[tid >> 6] = ss;
    __syncthreads();
    const float inv = 1.f / (EPS + sqrtf(wsum[0] + wsum[1] + wsum[2] + wsum[3]));
    float4 n; n.x = v.x * inv; n.y = v.y * inv; n.z = v.z * inv; n.w = v.w * inv;
    ((float4*)ql)[tid] = n;
    __syncthreads();
    float4 acc = {0.f, 0.f, 0.f, 0.f};
    const float4* Br = (const float4*)B + tid;  // row i: Br[i*256]
    for (int i = 0; i < 1024; ++i) {
        float4 br = Br[(size_t)i * 256];
        float qi = ql[i];
        acc.x += br.x * qi; acc.y += br.y * qi; acc.z += br.z * qi; acc.w += br.w * qi;
    }
    ((float4*)(w + (size_t)b * 1024))[tid] = acc;
}

#define FENCE asm volatile("" ::: "memory")

// ---- fused main (r4-proven): nsq GEMM (coarse counted-vmcnt) + pipelined finish ----
// grid = 256 blocks (1/CU), 512 threads (8 waves, 2M x 4N over 256x256 sub-tile).
__global__ __launch_bounds__(512, 2) void k_main2(const unsigned short* __restrict__ xbf,
                                                  const unsigned short* __restrict__ Bb,
                                                  const float* __restrict__ w,
                                                  float* __restrict__ outp,
                                                  float* __restrict__ sim_out) {
    __shared__ __align__(16) union {
        struct { unsigned short Xs[2][256 * 64]; unsigned short Bs[2][256 * 64]; } g;
        unsigned short xt2[2][32 * 1024];  // finish double buffer (2 x 64 KB)
    } S;
    __shared__ float nsq_s[256];
    __shared__ float wlds[1024];
    __shared__ float numer_s[32];
    __shared__ float simv[32];

    const int tid = threadIdx.x;
    const int lane = tid & 63;
    const int l15 = lane & 15, lg = lane >> 4;
    const int w8 = tid >> 6;
    const int wm = w8 >> 2, wn = w8 & 3;
    const int bx = blockIdx.x;
    const size_t tok0 = (size_t)bx * 256;
    const int b = bx >> 4;

    ((float2*)wlds)[tid] = ((const float2*)(w + (size_t)b * 1024))[tid];
    if (tid < 256) nsq_s[tid] = 0.f;
    __syncthreads();  // init visible before any use

    // stage step s (mt=s>>4, ks=s&15) into buffer buf: 8 gll16/thread, linear
    // LDS dest, pre-swizzled source chunk c^(row&7) (both-sides-or-neither).
#define STAGE(s_, buf_)                                                                  \
    do {                                                                                 \
        const int mt_ = (s_) >> 4, ks_ = (s_) & 15;                                      \
        _Pragma("unroll") for (int it = 0; it < 4; ++it) {                               \
            const int g_ = it * 512 + tid;                                               \
            const int row_ = g_ >> 3, c_ = g_ & 7;                                       \
            const int csw_ = (c_ ^ (row_ & 7)) * 8;                                      \
            gll16(xbf + (tok0 + row_) * 1024 + ks_ * 64 + csw_,                          \
                  (char*)S.g.Xs[buf_] + (size_t)(it * 512 + (tid & ~63)) * 16);          \
            gll16(Bb + (size_t)(mt_ * 256 + row_) * 1024 + ks_ * 64 + csw_,              \
                  (char*)S.g.Bs[buf_] + (size_t)(it * 512 + (tid & ~63)) * 16);          \
        }                                                                                \
    } while (0)

    f32x4 acc[8][4];

    STAGE(0, 0);
    STAGE(1, 1);

    for (int s = 0; s < 64; ++s) {
        const int buf = s & 1;
        if ((s & 15) == 0) {
#pragma unroll
            for (int mi = 0; mi < 8; ++mi)
#pragma unroll
                for (int ni = 0; ni < 4; ++ni) acc[mi][ni] = (f32x4){0.f, 0.f, 0.f, 0.f};
        }
        // leading sync: drain this step's 8 loads (next step's 8 stay in flight)
        if (s < 62) asm volatile("s_waitcnt vmcnt(8)" ::: "memory");
        else        asm volatile("s_waitcnt vmcnt(0)" ::: "memory");
        __builtin_amdgcn_s_barrier();

        const char* xb = (const char*)S.g.Xs[buf] + (wm * 128 + l15) * 128;
        const char* bb = (const char*)S.g.Bs[buf] + (wn * 64 + l15) * 128;
        const int sw = (l15 & 7) << 4;

        bf16x8 bq[4][2];
#pragma unroll
        for (int ni = 0; ni < 4; ++ni)
#pragma unroll
            for (int kk = 0; kk < 2; ++kk)
                bq[ni][kk] = *(const bf16x8*)(bb + ni * 16 * 128 + ((kk * 64 + lg * 16) ^ sw));

        __builtin_amdgcn_s_setprio(1);
#pragma unroll
        for (int p = 0; p < 4; ++p) {
            bf16x8 a[2][2];
#pragma unroll
            for (int mi = 0; mi < 2; ++mi)
#pragma unroll
                for (int kk = 0; kk < 2; ++kk)
                    a[mi][kk] = *(const bf16x8*)(xb + (p * 2 + mi) * 16 * 128 +
                                                 ((kk * 64 + lg * 16) ^ sw));
#pragma unroll
            for (int mi = 0; mi < 2; ++mi)
#pragma unroll
                for (int ni = 0; ni < 4; ++ni)
#pragma unroll
                    for (int kk = 0; kk < 2; ++kk)
                        acc[p * 2 + mi][ni] = __builtin_amdgcn_mfma_f32_16x16x32_bf16(
                            a[mi][kk], bq[ni][kk], acc[p * 2 + mi][ni], 0, 0, 0);
        }
        __builtin_amdgcn_s_setprio(0);

        FENCE;
        __builtin_amdgcn_s_barrier();  // all waves done reading buf; safe to overwrite
        FENCE;
        if (s + 2 < 64) STAGE(s + 2, buf);

        if ((s & 15) == 15) {  // end of m-tile: fold squares, reduce, LDS-atomic
#pragma unroll
            for (int mi = 0; mi < 8; ++mi)
#pragma unroll
                for (int r = 0; r < 4; ++r) {
                    float v = 0.f;
#pragma unroll
                    for (int ni = 0; ni < 4; ++ni) v += acc[mi][ni][r] * acc[mi][ni][r];
                    v += __shfl_xor(v, 1);
                    v += __shfl_xor(v, 2);
                    v += __shfl_xor(v, 4);
                    v += __shfl_xor(v, 8);
                    if (l15 == 0) atomicAdd(&nsq_s[wm * 128 + mi * 16 + lg * 4 + r], v);
                }
        }
    }
#undef STAGE

    // ---- pipelined finish: per 32-token sub-tile: numer, sim, out-partial ----
    // sub-tile = 32 tok x 1024 cols bf16 = 64 KB; double-buffered in the union.
#define STAGE_SUB(sub_, bf_)                                                             \
    do {                                                                                 \
        _Pragma("unroll") for (int it = 0; it < 8; ++it) {                               \
            const int idx_ = it * 512 + tid;                                             \
            const int row_ = idx_ >> 7, c_ = idx_ & 127;                                 \
            gll16(xbf + (tok0 + (sub_) * 32 + row_) * 1024 + ((c_ ^ (row_ & 7)) * 8),    \
                  (char*)S.xt2[bf_] + (size_t)(it * 512 + (tid & ~63)) * 16);            \
        }                                                                                \
    } while (0)

    // GEMM loop ended with a trailing barrier (and vmcnt(0) at s=62/63): union is
    // free. Issue sub-0 stage now so it overlaps the nsq visibility sync below.
    STAGE_SUB(0, 0);
    asm volatile("s_waitcnt lgkmcnt(0)" ::: "memory");
    __builtin_amdgcn_s_barrier();  // nsq_s atomics visible to all waves

    float oa0 = 0.f, oa1 = 0.f;
    for (int sub = 0; sub < 8; ++sub) {
        const int cur = sub & 1;
        if (sub < 7) STAGE_SUB(sub + 1, cur ^ 1);  // issue next before waiting on cur
        if (sub < 7) asm volatile("s_waitcnt vmcnt(8)" ::: "memory");
        else         asm volatile("s_waitcnt vmcnt(0)" ::: "memory");
        __builtin_amdgcn_s_barrier();  // cur buffer fully staged

        const char* xt = (const char*)S.xt2[cur];
        {   // numer: 16 lanes per token
            const int t = tid >> 4, kp = tid & 15;
            const char* pt = xt + t * 2048;
            const int sw2 = (t & 7) << 4;
            float acc2 = 0.f;
#pragma unroll
            for (int j = 0; j < 8; ++j) {
                bf16x8 v = *(const bf16x8*)(pt + ((j * 256 + kp * 16) ^ sw2));
                const float* wp = wlds + j * 128 + kp * 8;
#pragma unroll
                for (int e = 0; e < 8; ++e) acc2 += (float)v[e] * wp[e];
            }
            acc2 += __shfl_xor(acc2, 1);
            acc2 += __shfl_xor(acc2, 2);
            acc2 += __shfl_xor(acc2, 4);
            acc2 += __shfl_xor(acc2, 8);
            if (kp == 0) numer_s[t] = acc2;
        }
        asm volatile("s_waitcnt lgkmcnt(0)" ::: "memory");
        __builtin_amdgcn_s_barrier();

        if (tid < 32) {
            float sv = numer_s[tid] / (EPS + sqrtf(nsq_s[sub * 32 + tid]));
            simv[tid] = sv;
            sim_out[tok0 + sub * 32 + tid] = sv;
        }
        asm volatile("s_waitcnt lgkmcnt(0)" ::: "memory");
        __builtin_amdgcn_s_barrier();

        {   // out partial: each lane owns 2 columns
            const int nb = tid * 4;
#pragma unroll 4
            for (int t = 0; t < 32; ++t) {
                bf16x2 v = *(const bf16x2*)(xt + t * 2048 + (nb ^ ((t & 7) << 4)));
                float sv = simv[t];
                oa0 += sv * (float)v[0];
                oa1 += sv * (float)v[1];
            }
        }
        asm volatile("s_waitcnt lgkmcnt(0)" ::: "memory");
        __builtin_amdgcn_s_barrier();  // cur reads retired; next stage may overwrite
    }
#undef STAGE_SUB
    float2 o; o.x = oa0; o.y = oa1;
    ((float2*)(outp + (size_t)bx * 1024))[tid] = o;
}

// ---- fallback pass 3 (no xbf workspace): 128x128 tile from f32 x ----
__global__ __launch_bounds__(256, 2) void k_nsq_f32(const float* __restrict__ x,
                                                    const unsigned short* __restrict__ Bb,
                                                    float* __restrict__ nsq_g) {
    __shared__ unsigned short Xs[128 * 64];
    __shared__ unsigned short Bs[128 * 64];
    __shared__ float nsq_s[128];

    const int tid = threadIdx.x;
    const int lane = tid & 63;
    const int l15 = lane & 15, lg = lane >> 4;
    const int w = tid >> 6;
    const int wr = w >> 1, wc = w & 1;
    const int st = blockIdx.x * 128;
    const int mh = blockIdx.y;

    float nsq_reg[4][4];
#pragma unroll
    for (int mi = 0; mi < 4; ++mi)
#pragma unroll
        for (int r = 0; r < 4; ++r) nsq_reg[mi][r] = 0.f;

    for (int mti = 0; mti < 4; ++mti) {
        const int mt = mh * 4 + mti;
        f32x4 acc[4][4];
#pragma unroll
        for (int mi = 0; mi < 4; ++mi)
#pragma unroll
            for (int ni = 0; ni < 4; ++ni) acc[mi][ni] = (f32x4){0.f, 0.f, 0.f, 0.f};

        for (int ks = 0; ks < 16; ++ks) {
            __syncthreads();
            {
                const int row = tid >> 1, kh = tid & 1;
                const float* srcx = x + (size_t)(st + row) * 1024 + ks * 64 + kh * 32;
                char* ldsrow = (char*)Xs + row * 128;
                const int sw = (row & 7) << 4;
#pragma unroll
                for (int j = 0; j < 4; ++j) {
                    float4 v0 = ((const float4*)srcx)[j * 2];
                    float4 v1 = ((const float4*)srcx)[j * 2 + 1];
                    uint4 p;
                    p.x = f2bf(v0.x) | (f2bf(v0.y) << 16);
                    p.y = f2bf(v0.z) | (f2bf(v0.w) << 16);
                    p.z = f2bf(v1.x) | (f2bf(v1.y) << 16);
                    p.w = f2bf(v1.z) | (f2bf(v1.w) << 16);
                    *(uint4*)(ldsrow + (((kh * 4 + j) * 16) ^ sw)) = p;
                }
#pragma unroll
                for (int it = 0; it < 4; ++it) {
                    const int idx = it * 256 + tid;
                    const int brow = idx >> 3, c = idx & 7;
                    char* baseB = (char*)Bs + (size_t)(it * 256 + (tid & ~63)) * 16;
                    gll16(Bb + (size_t)(mt * 128 + brow) * 1024 + ks * 64 + (c ^ (brow & 7)) * 8,
                          baseB);
                }
            }
            __syncthreads();

            const char* xb = (const char*)Xs + (wr * 64 + l15) * 128;
            const char* bb = (const char*)Bs + (wc * 64 + l15) * 128;
            const int sw = (l15 & 7) << 4;
#pragma unroll
            for (int kk = 0; kk < 2; ++kk) {
                const int ob = (kk * 64 + lg * 16) ^ sw;
                bf16x8 a[4], bq[4];
#pragma unroll
                for (int mi = 0; mi < 4; ++mi) a[mi] = *(const bf16x8*)(xb + mi * 2048 + ob);
#pragma unroll
                for (int ni = 0; ni < 4; ++ni) bq[ni] = *(const bf16x8*)(bb + ni * 2048 + ob);
#pragma unroll
                for (int mi = 0; mi < 4; ++mi)
#pragma unroll
                    for (int ni = 0; ni < 4; ++ni)
                        acc[mi][ni] = __builtin_amdgcn_mfma_f32_16x16x32_bf16(
                            a[mi], bq[ni], acc[mi][ni], 0, 0, 0);
            }
        }
#pragma unroll
        for (int mi = 0; mi < 4; ++mi)
#pragma unroll
            for (int ni = 0; ni < 4; ++ni)
#pragma unroll
                for (int r = 0; r < 4; ++r)
                    nsq_reg[mi][r] += acc[mi][ni][r] * acc[mi][ni][r];
    }

    if (tid < 128) nsq_s[tid] = 0.f;
    __syncthreads();
#pragma unroll
    for (int mi = 0; mi < 4; ++mi)
#pragma unroll
        for (int r = 0; r < 4; ++r) {
            float v = nsq_reg[mi][r];
            v += __shfl_xor(v, 1);
            v += __shfl_xor(v, 2);
            v += __shfl_xor(v, 4);
            v += __shfl_xor(v, 8);
            if (l15 == 0) atomicAdd(&nsq_s[wr * 64 + mi * 16 + lg * 4 + r], v);
        }
    __syncthreads();
    if (tid < 128) nsq_g[(size_t)mh * 65536 + st + tid] = nsq_s[tid];
}

// ---- fallback pass 4 ----
__global__ __launch_bounds__(256, 2) void k_finish0(
    const float* __restrict__ x, const float* __restrict__ w,
    const float* __restrict__ nsq_g, float* __restrict__ outp,
    float* __restrict__ sim_out) {
    __shared__ __align__(16) unsigned short xt[32 * 1024];
    __shared__ float numer[32];
    __shared__ float simv[32];

    const int tid = threadIdx.x;
    const int bs = blockIdx.x;
    const int b = bs >> 7, s0 = (bs & 127) * 32;
    const size_t tok0 = (size_t)b * 4096 + s0;

    const float4* src = (const float4*)(x + tok0 * 1024) + tid;
    char* lds = (char*)xt;
    for (int r = 0; r < 32; ++r) {
        float4 v = src[r * 256];
        uint2 p;
        p.x = f2bf(v.x) | (f2bf(v.y) << 16);
        p.y = f2bf(v.z) | (f2bf(v.w) << 16);
        *(uint2*)(lds + r * 2048 + ((tid * 8) ^ ((r & 7) << 4))) = p;
    }
    __syncthreads();

    {
        const int t = tid >> 3, kp = tid & 7;
        const float* wb = w + (size_t)b * 1024 + kp * 128;
        const char* pt = (const char*)xt + t * 2048;
        const int sw2 = (t & 7) << 4;
        float acc = 0.f;
#pragma unroll
        for (int j = 0; j < 16; ++j) {
            const int kb = (kp * 128 + j * 8) * 2;
            bf16x8 v = *(const bf16x8*)(pt + (kb ^ sw2));
#pragma unroll
            for (int e = 0; e < 8; ++e) acc += (float)v[e] * wb[j * 8 + e];
        }
        acc += __shfl_xor(acc, 1);
        acc += __shfl_xor(acc, 2);
        acc += __shfl_xor(acc, 4);
        if (kp == 0) numer[t] = acc;
    }
    __syncthreads();

    if (tid < 32) {
        float nt = nsq_g[tok0 + tid] + nsq_g[65536 + tok0 + tid];
        float s = numer[tid] / (EPS + sqrtf(nt));
        simv[tid] = s;
        sim_out[tok0 + tid] = s;
    }
    __syncthreads();

    {
        const int n0 = tid * 4;
        float a0 = 0.f, a1 = 0.f, a2 = 0.f, a3 = 0.f;
        const char* p = (const char*)xt;
#pragma unroll 4
        for (int t = 0; t < 32; ++t) {
            int byte = t * 2048 + ((n0 * 2) ^ ((t & 7) << 4));
            bf16x4 v = *(const bf16x4*)(p + byte);
            float s = simv[t];
            a0 += s * (float)v[0];
            a1 += s * (float)v[1];
            a2 += s * (float)v[2];
            a3 += s * (float)v[3];
        }
        float4 o; o.x = a0; o.y = a1; o.z = a2; o.w = a3;
        ((float4*)(outp + (size_t)bs * 1024))[tid] = o;
    }
}

// ---- out[b][j] = sum over NT tile partials ----
template <int NT>
__global__ void k_outred(const float* __restrict__ outp, float* __restrict__ out) {
    const int b = blockIdx.y, j = blockIdx.x * 256 + threadIdx.x;
    const float* p = outp + (size_t)b * NT * 1024 + j;
    float s = 0.f;
    for (int t = 0; t < NT; ++t) s += p[t * 1024];
    out[b * 1024 + j] = s;
}

extern "C" void kernel_launch(void* const* d_in, const int* in_sizes, int n_in,
                              void* d_out, int out_size, void* d_ws, size_t ws_size,
                              hipStream_t stream) {
    const float* x = (const float*)d_in[0];  // [16][4096][1024]
    const float* A = (const float*)d_in[1];  // [1024][1024]
    const float* B = (const float*)d_in[2];  // [1024][1024]
    float* out = (float*)d_out;              // [16][1024] then sim [16][4096]
    float* sim = out + 16 * 1024;
    float* ws = (float*)d_ws;
    float* xs_part = ws;                                  // 524288  (2 MB)
    float* q = ws + 540672;                               // 16384
    float* wv = ws + 557056;                              // 16384
    float* nsq = ws + 573440;                             // 131072 (fallback only)
    float* outp = ws + 704512;                            // up to 8 MB
    unsigned short* Bb = (unsigned short*)(ws + 2801664); // 1M bf16 (2 MB)
    unsigned short* xbf = (unsigned short*)(ws + 3325952);// 64M bf16 (128 MB, optional)
    const bool xb = ws_size >= (size_t)(3325952 + 33554432) * 4;

    if (xb) {
        k_prep<1><<<dim3(32, 16), 256, 0, stream>>>(x, xs_part, xbf);
        k_glue<<<1088, 256, 0, stream>>>(B, Bb, xs_part, A, q);
        k_wf<<<16, 256, 0, stream>>>(B, q, wv);
        k_main2<<<256, 512, 0, stream>>>(xbf, Bb, wv, outp, sim);
        k_outred<16><<<dim3(4, 16), 256, 0, stream>>>(outp, out);
    } else {
        k_prep<0><<<dim3(32, 16), 256, 0, stream>>>(x, xs_part, (unsigned short*)0);
        k_glue<<<1088, 256, 0, stream>>>(B, Bb, xs_part, A, q);
        k_wf<<<16, 256, 0, stream>>>(B, q, wv);
        k_nsq_f32<<<dim3(512, 2), 256, 0, stream>>>(x, Bb, nsq);
        k_finish0<<<2048, 256, 0, stream>>>(x, wv, nsq, outp, sim);
        k_outred<128><<<dim3(4, 16), 256, 0, stream>>>(outp, out);
    }
}

// Round 11
// 301.652 us; speedup vs baseline: 1.1419x; 1.0798x over previous
//
#include <hip/hip_runtime.h>

#define EPS 1e-5f

typedef __bf16 bf16x8 __attribute__((ext_vector_type(8)));
typedef __bf16 bf16x4 __attribute__((ext_vector_type(4)));
typedef __bf16 bf16x2 __attribute__((ext_vector_type(2)));
typedef float f32x4 __attribute__((ext_vector_type(4)));

static __device__ __forceinline__ unsigned int f2bf(float f) {
    unsigned int u = __builtin_bit_cast(unsigned int, f);
    u = (u + 0x7fffu + ((u >> 16) & 1u)) >> 16;
    return u;
}

// async global->LDS, 16B per lane. LDS dest is wave-uniform base (+lane*16 by HW).
static __device__ __forceinline__ void gll16(const void* g, void* l) {
    __builtin_amdgcn_global_load_lds(
        (const __attribute__((address_space(1))) unsigned int*)(unsigned long long)g,
        (__attribute__((address_space(3))) unsigned int*)(unsigned int)(unsigned long long)l,
        16, 0, 0);
}

// ---- pass 1: colsum partials (+ optional bf16 copy of x) ----
template <int XBF>
__global__ __launch_bounds__(256) void k_prep(const float* __restrict__ x,
                                              float* __restrict__ xs_part,
                                              unsigned short* __restrict__ xbf) {
    const int b = blockIdx.y, sc = blockIdx.x, tid = threadIdx.x;
    const size_t rowbase = ((size_t)(b * 4096 + sc * 128)) * 1024;
    const float4* src = (const float4*)(x + rowbase) + tid;
    uint2* dst = XBF ? ((uint2*)(xbf + rowbase) + tid) : (uint2*)0;
    float ax = 0.f, ay = 0.f, az = 0.f, aw = 0.f;
    for (int r = 0; r < 128; ++r) {
        float4 v = src[r * 256];
        ax += v.x; ay += v.y; az += v.z; aw += v.w;
        if (XBF) {
            uint2 p;
            p.x = f2bf(v.x) | (f2bf(v.y) << 16);
            p.y = f2bf(v.z) | (f2bf(v.w) << 16);
            dst[r * 256] = p;
        }
    }
    float4 o; o.x = ax; o.y = ay; o.z = az; o.w = aw;
    ((float4*)(xs_part + ((size_t)(b * 32 + sc)) * 1024))[tid] = o;
}

// ---- merged: B->bf16 convert (blocks 0..1023) + xsred+query (blocks 1024..1087) ----
__global__ __launch_bounds__(256) void k_glue(const float* __restrict__ B,
                                              unsigned short* __restrict__ Bb,
                                              const float* __restrict__ xs_part,
                                              const float* __restrict__ A,
                                              float* __restrict__ q) {
    __shared__ float xsl[1024];
    const int blk = blockIdx.x, tid = threadIdx.x;
    if (blk < 1024) {
        const int i = blk * 256 + tid;
        float4 v = ((const float4*)B)[i];
        uint2 p;
        p.x = f2bf(v.x) | (f2bf(v.y) << 16);
        p.y = f2bf(v.z) | (f2bf(v.w) << 16);
        ((uint2*)Bb)[i] = p;
        return;
    }
    const int gb = blk - 1024;
    const int g = gb & 3, b = gb >> 2;
    {
        float4 s4 = {0.f, 0.f, 0.f, 0.f};
        const float4* p = (const float4*)(xs_part + (size_t)b * 32768) + tid;
        for (int sc = 0; sc < 32; ++sc) {
            float4 v = p[sc * 256];
            s4.x += v.x; s4.y += v.y; s4.z += v.z; s4.w += v.w;
        }
        ((float4*)xsl)[tid] = s4;
    }
    __syncthreads();
    const int i = g * 256 + tid;
    const float4* ar = (const float4*)(A + (size_t)i * 1024);
    float acc = 0.f;
    for (int k = 0; k < 256; ++k) {
        float4 a = ar[k], v = ((const float4*)xsl)[k];
        acc += a.x * v.x + a.y * v.y + a.z * v.z + a.w * v.w;
    }
    q[b * 1024 + i] = acc;
}

// ---- fused qnorm + w (r4-proven column version, 64 blocks) ----
// w[b,j] = sum_i B[i,j] * (q[b,i]/||q[b]||)
__global__ __launch_bounds__(256) void k_wf(const float* __restrict__ B,
                                            const float* __restrict__ q,
                                            float* __restrict__ w) {
    __shared__ float ql[1024];
    __shared__ float wsum[4];
    const int b = blockIdx.y, g = blockIdx.x, tid = threadIdx.x;
    float4 v = ((const float4*)(q + (size_t)b * 1024))[tid];
    float ss = v.x * v.x + v.y * v.y + v.z * v.z + v.w * v.w;
    for (int o = 1; o < 64; o <<= 1) ss += __shfl_xor(ss, o);
    if ((tid & 63) == 0) wsum[tid >> 6] = ss;
    __syncthreads();
    const float inv = 1.f / (EPS + sqrtf(wsum[0] + wsum[1] + wsum[2] + wsum[3]));
    float4 n; n.x = v.x * inv; n.y = v.y * inv; n.z = v.z * inv; n.w = v.w * inv;
    ((float4*)ql)[tid] = n;
    __syncthreads();
    const int j = g * 256 + tid;
    float acc = 0.f;
    for (int i = 0; i < 1024; ++i) acc += B[(size_t)i * 1024 + j] * ql[i];
    w[b * 1024 + j] = acc;
}

#define FENCE asm volatile("" ::: "memory")

// ---- fused main (r4-proven): nsq GEMM (coarse counted-vmcnt) + pipelined finish ----
// grid = 256 blocks (1/CU), 512 threads (8 waves, 2M x 4N over 256x256 sub-tile).
__global__ __launch_bounds__(512, 2) void k_main2(const unsigned short* __restrict__ xbf,
                                                  const unsigned short* __restrict__ Bb,
                                                  const float* __restrict__ w,
                                                  float* __restrict__ outp,
                                                  float* __restrict__ sim_out) {
    __shared__ __align__(16) union {
        struct { unsigned short Xs[2][256 * 64]; unsigned short Bs[2][256 * 64]; } g;
        unsigned short xt2[2][32 * 1024];  // finish double buffer (2 x 64 KB)
    } S;
    __shared__ float nsq_s[256];
    __shared__ float wlds[1024];
    __shared__ float numer_s[32];
    __shared__ float simv[32];

    const int tid = threadIdx.x;
    const int lane = tid & 63;
    const int l15 = lane & 15, lg = lane >> 4;
    const int w8 = tid >> 6;
    const int wm = w8 >> 2, wn = w8 & 3;
    const int bx = blockIdx.x;
    const size_t tok0 = (size_t)bx * 256;
    const int b = bx >> 4;

    ((float2*)wlds)[tid] = ((const float2*)(w + (size_t)b * 1024))[tid];
    if (tid < 256) nsq_s[tid] = 0.f;
    __syncthreads();  // init visible before any use

    // stage step s (mt=s>>4, ks=s&15) into buffer buf: 8 gll16/thread, linear
    // LDS dest, pre-swizzled source chunk c^(row&7) (both-sides-or-neither).
#define STAGE(s_, buf_)                                                                  \
    do {                                                                                 \
        const int mt_ = (s_) >> 4, ks_ = (s_) & 15;                                      \
        _Pragma("unroll") for (int it = 0; it < 4; ++it) {                               \
            const int g_ = it * 512 + tid;                                               \
            const int row_ = g_ >> 3, c_ = g_ & 7;                                       \
            const int csw_ = (c_ ^ (row_ & 7)) * 8;                                      \
            gll16(xbf + (tok0 + row_) * 1024 + ks_ * 64 + csw_,                          \
                  (char*)S.g.Xs[buf_] + (size_t)(it * 512 + (tid & ~63)) * 16);          \
            gll16(Bb + (size_t)(mt_ * 256 + row_) * 1024 + ks_ * 64 + csw_,              \
                  (char*)S.g.Bs[buf_] + (size_t)(it * 512 + (tid & ~63)) * 16);          \
        }                                                                                \
    } while (0)

    f32x4 acc[8][4];

    STAGE(0, 0);
    STAGE(1, 1);

    for (int s = 0; s < 64; ++s) {
        const int buf = s & 1;
        if ((s & 15) == 0) {
#pragma unroll
            for (int mi = 0; mi < 8; ++mi)
#pragma unroll
                for (int ni = 0; ni < 4; ++ni) acc[mi][ni] = (f32x4){0.f, 0.f, 0.f, 0.f};
        }
        // leading sync: drain this step's 8 loads (next step's 8 stay in flight)
        if (s < 62) asm volatile("s_waitcnt vmcnt(8)" ::: "memory");
        else        asm volatile("s_waitcnt vmcnt(0)" ::: "memory");
        __builtin_amdgcn_s_barrier();

        const char* xb = (const char*)S.g.Xs[buf] + (wm * 128 + l15) * 128;
        const char* bb = (const char*)S.g.Bs[buf] + (wn * 64 + l15) * 128;
        const int sw = (l15 & 7) << 4;

        bf16x8 bq[4][2];
#pragma unroll
        for (int ni = 0; ni < 4; ++ni)
#pragma unroll
            for (int kk = 0; kk < 2; ++kk)
                bq[ni][kk] = *(const bf16x8*)(bb + ni * 16 * 128 + ((kk * 64 + lg * 16) ^ sw));

        __builtin_amdgcn_s_setprio(1);
#pragma unroll
        for (int p = 0; p < 4; ++p) {
            bf16x8 a[2][2];
#pragma unroll
            for (int mi = 0; mi < 2; ++mi)
#pragma unroll
                for (int kk = 0; kk < 2; ++kk)
                    a[mi][kk] = *(const bf16x8*)(xb + (p * 2 + mi) * 16 * 128 +
                                                 ((kk * 64 + lg * 16) ^ sw));
#pragma unroll
            for (int mi = 0; mi < 2; ++mi)
#pragma unroll
                for (int ni = 0; ni < 4; ++ni)
#pragma unroll
                    for (int kk = 0; kk < 2; ++kk)
                        acc[p * 2 + mi][ni] = __builtin_amdgcn_mfma_f32_16x16x32_bf16(
                            a[mi][kk], bq[ni][kk], acc[p * 2 + mi][ni], 0, 0, 0);
        }
        __builtin_amdgcn_s_setprio(0);

        FENCE;
        __builtin_amdgcn_s_barrier();  // all waves done reading buf; safe to overwrite
        FENCE;
        if (s + 2 < 64) STAGE(s + 2, buf);

        if ((s & 15) == 15) {  // end of m-tile: fold squares, reduce, LDS-atomic
#pragma unroll
            for (int mi = 0; mi < 8; ++mi)
#pragma unroll
                for (int r = 0; r < 4; ++r) {
                    float v = 0.f;
#pragma unroll
                    for (int ni = 0; ni < 4; ++ni) v += acc[mi][ni][r] * acc[mi][ni][r];
                    v += __shfl_xor(v, 1);
                    v += __shfl_xor(v, 2);
                    v += __shfl_xor(v, 4);
                    v += __shfl_xor(v, 8);
                    if (l15 == 0) atomicAdd(&nsq_s[wm * 128 + mi * 16 + lg * 4 + r], v);
                }
        }
    }
#undef STAGE

    // ---- pipelined finish: per 32-token sub-tile: numer, sim, out-partial ----
    // sub-tile = 32 tok x 1024 cols bf16 = 64 KB; double-buffered in the union.
#define STAGE_SUB(sub_, bf_)                                                             \
    do {                                                                                 \
        _Pragma("unroll") for (int it = 0; it < 8; ++it) {                               \
            const int idx_ = it * 512 + tid;                                             \
            const int row_ = idx_ >> 7, c_ = idx_ & 127;                                 \
            gll16(xbf + (tok0 + (sub_) * 32 + row_) * 1024 + ((c_ ^ (row_ & 7)) * 8),    \
                  (char*)S.xt2[bf_] + (size_t)(it * 512 + (tid & ~63)) * 16);            \
        }                                                                                \
    } while (0)

    // GEMM loop ended with a trailing barrier (and vmcnt(0) at s=62/63): union is
    // free. Issue sub-0 stage now so it overlaps the nsq visibility sync below.
    STAGE_SUB(0, 0);
    asm volatile("s_waitcnt lgkmcnt(0)" ::: "memory");
    __builtin_amdgcn_s_barrier();  // nsq_s atomics visible to all waves

    float oa0 = 0.f, oa1 = 0.f;
    for (int sub = 0; sub < 8; ++sub) {
        const int cur = sub & 1;
        if (sub < 7) STAGE_SUB(sub + 1, cur ^ 1);  // issue next before waiting on cur
        if (sub < 7) asm volatile("s_waitcnt vmcnt(8)" ::: "memory");
        else         asm volatile("s_waitcnt vmcnt(0)" ::: "memory");
        __builtin_amdgcn_s_barrier();  // cur buffer fully staged

        const char* xt = (const char*)S.xt2[cur];
        {   // numer: 16 lanes per token
            const int t = tid >> 4, kp = tid & 15;
            const char* pt = xt + t * 2048;
            const int sw2 = (t & 7) << 4;
            float acc2 = 0.f;
#pragma unroll
            for (int j = 0; j < 8; ++j) {
                bf16x8 v = *(const bf16x8*)(pt + ((j * 256 + kp * 16) ^ sw2));
                const float* wp = wlds + j * 128 + kp * 8;
#pragma unroll
                for (int e = 0; e < 8; ++e) acc2 += (float)v[e] * wp[e];
            }
            acc2 += __shfl_xor(acc2, 1);
            acc2 += __shfl_xor(acc2, 2);
            acc2 += __shfl_xor(acc2, 4);
            acc2 += __shfl_xor(acc2, 8);
            if (kp == 0) numer_s[t] = acc2;
        }
        asm volatile("s_waitcnt lgkmcnt(0)" ::: "memory");
        __builtin_amdgcn_s_barrier();

        if (tid < 32) {
            float sv = numer_s[tid] / (EPS + sqrtf(nsq_s[sub * 32 + tid]));
            simv[tid] = sv;
            sim_out[tok0 + sub * 32 + tid] = sv;
        }
        asm volatile("s_waitcnt lgkmcnt(0)" ::: "memory");
        __builtin_amdgcn_s_barrier();

        {   // out partial: each lane owns 2 columns
            const int nb = tid * 4;
#pragma unroll 4
            for (int t = 0; t < 32; ++t) {
                bf16x2 v = *(const bf16x2*)(xt + t * 2048 + (nb ^ ((t & 7) << 4)));
                float sv = simv[t];
                oa0 += sv * (float)v[0];
                oa1 += sv * (float)v[1];
            }
        }
        asm volatile("s_waitcnt lgkmcnt(0)" ::: "memory");
        __builtin_amdgcn_s_barrier();  // cur reads retired; next stage may overwrite
    }
#undef STAGE_SUB
    float2 o; o.x = oa0; o.y = oa1;
    ((float2*)(outp + (size_t)bx * 1024))[tid] = o;
}

// ---- fallback pass 3 (no xbf workspace): 128x128 tile from f32 x ----
__global__ __launch_bounds__(256, 2) void k_nsq_f32(const float* __restrict__ x,
                                                    const unsigned short* __restrict__ Bb,
                                                    float* __restrict__ nsq_g) {
    __shared__ unsigned short Xs[128 * 64];
    __shared__ unsigned short Bs[128 * 64];
    __shared__ float nsq_s[128];

    const int tid = threadIdx.x;
    const int lane = tid & 63;
    const int l15 = lane & 15, lg = lane >> 4;
    const int w = tid >> 6;
    const int wr = w >> 1, wc = w & 1;
    const int st = blockIdx.x * 128;
    const int mh = blockIdx.y;

    float nsq_reg[4][4];
#pragma unroll
    for (int mi = 0; mi < 4; ++mi)
#pragma unroll
        for (int r = 0; r < 4; ++r) nsq_reg[mi][r] = 0.f;

    for (int mti = 0; mti < 4; ++mti) {
        const int mt = mh * 4 + mti;
        f32x4 acc[4][4];
#pragma unroll
        for (int mi = 0; mi < 4; ++mi)
#pragma unroll
            for (int ni = 0; ni < 4; ++ni) acc[mi][ni] = (f32x4){0.f, 0.f, 0.f, 0.f};

        for (int ks = 0; ks < 16; ++ks) {
            __syncthreads();
            {
                const int row = tid >> 1, kh = tid & 1;
                const float* srcx = x + (size_t)(st + row) * 1024 + ks * 64 + kh * 32;
                char* ldsrow = (char*)Xs + row * 128;
                const int sw = (row & 7) << 4;
#pragma unroll
                for (int j = 0; j < 4; ++j) {
                    float4 v0 = ((const float4*)srcx)[j * 2];
                    float4 v1 = ((const float4*)srcx)[j * 2 + 1];
                    uint4 p;
                    p.x = f2bf(v0.x) | (f2bf(v0.y) << 16);
                    p.y = f2bf(v0.z) | (f2bf(v0.w) << 16);
                    p.z = f2bf(v1.x) | (f2bf(v1.y) << 16);
                    p.w = f2bf(v1.z) | (f2bf(v1.w) << 16);
                    *(uint4*)(ldsrow + (((kh * 4 + j) * 16) ^ sw)) = p;
                }
#pragma unroll
                for (int it = 0; it < 4; ++it) {
                    const int idx = it * 256 + tid;
                    const int brow = idx >> 3, c = idx & 7;
                    char* baseB = (char*)Bs + (size_t)(it * 256 + (tid & ~63)) * 16;
                    gll16(Bb + (size_t)(mt * 128 + brow) * 1024 + ks * 64 + (c ^ (brow & 7)) * 8,
                          baseB);
                }
            }
            __syncthreads();

            const char* xb = (const char*)Xs + (wr * 64 + l15) * 128;
            const char* bb = (const char*)Bs + (wc * 64 + l15) * 128;
            const int sw = (l15 & 7) << 4;
#pragma unroll
            for (int kk = 0; kk < 2; ++kk) {
                const int ob = (kk * 64 + lg * 16) ^ sw;
                bf16x8 a[4], bq[4];
#pragma unroll
                for (int mi = 0; mi < 4; ++mi) a[mi] = *(const bf16x8*)(xb + mi * 2048 + ob);
#pragma unroll
                for (int ni = 0; ni < 4; ++ni) bq[ni] = *(const bf16x8*)(bb + ni * 2048 + ob);
#pragma unroll
                for (int mi = 0; mi < 4; ++mi)
#pragma unroll
                    for (int ni = 0; ni < 4; ++ni)
                        acc[mi][ni] = __builtin_amdgcn_mfma_f32_16x16x32_bf16(
                            a[mi], bq[ni], acc[mi][ni], 0, 0, 0);
            }
        }
#pragma unroll
        for (int mi = 0; mi < 4; ++mi)
#pragma unroll
            for (int ni = 0; ni < 4; ++ni)
#pragma unroll
                for (int r = 0; r < 4; ++r)
                    nsq_reg[mi][r] += acc[mi][ni][r] * acc[mi][ni][r];
    }

    if (tid < 128) nsq_s[tid] = 0.f;
    __syncthreads();
#pragma unroll
    for (int mi = 0; mi < 4; ++mi)
#pragma unroll
        for (int r = 0; r < 4; ++r) {
            float v = nsq_reg[mi][r];
            v += __shfl_xor(v, 1);
            v += __shfl_xor(v, 2);
            v += __shfl_xor(v, 4);
            v += __shfl_xor(v, 8);
            if (l15 == 0) atomicAdd(&nsq_s[wr * 64 + mi * 16 + lg * 4 + r], v);
        }
    __syncthreads();
    if (tid < 128) nsq_g[(size_t)mh * 65536 + st + tid] = nsq_s[tid];
}

// ---- fallback pass 4 ----
__global__ __launch_bounds__(256, 2) void k_finish0(
    const float* __restrict__ x, const float* __restrict__ w,
    const float* __restrict__ nsq_g, float* __restrict__ outp,
    float* __restrict__ sim_out) {
    __shared__ __align__(16) unsigned short xt[32 * 1024];
    __shared__ float numer[32];
    __shared__ float simv[32];

    const int tid = threadIdx.x;
    const int bs = blockIdx.x;
    const int b = bs >> 7, s0 = (bs & 127) * 32;
    const size_t tok0 = (size_t)b * 4096 + s0;

    const float4* src = (const float4*)(x + tok0 * 1024) + tid;
    char* lds = (char*)xt;
    for (int r = 0; r < 32; ++r) {
        float4 v = src[r * 256];
        uint2 p;
        p.x = f2bf(v.x) | (f2bf(v.y) << 16);
        p.y = f2bf(v.z) | (f2bf(v.w) << 16);
        *(uint2*)(lds + r * 2048 + ((tid * 8) ^ ((r & 7) << 4))) = p;
    }
    __syncthreads();

    {
        const int t = tid >> 3, kp = tid & 7;
        const float* wb = w + (size_t)b * 1024 + kp * 128;
        const char* pt = (const char*)xt + t * 2048;
        const int sw2 = (t & 7) << 4;
        float acc = 0.f;
#pragma unroll
        for (int j = 0; j < 16; ++j) {
            const int kb = (kp * 128 + j * 8) * 2;
            bf16x8 v = *(const bf16x8*)(pt + (kb ^ sw2));
#pragma unroll
            for (int e = 0; e < 8; ++e) acc += (float)v[e] * wb[j * 8 + e];
        }
        acc += __shfl_xor(acc, 1);
        acc += __shfl_xor(acc, 2);
        acc += __shfl_xor(acc, 4);
        if (kp == 0) numer[t] = acc;
    }
    __syncthreads();

    if (tid < 32) {
        float nt = nsq_g[tok0 + tid] + nsq_g[65536 + tok0 + tid];
        float s = numer[tid] / (EPS + sqrtf(nt));
        simv[tid] = s;
        sim_out[tok0 + tid] = s;
    }
    __syncthreads();

    {
        const int n0 = tid * 4;
        float a0 = 0.f, a1 = 0.f, a2 = 0.f, a3 = 0.f;
        const char* p = (const char*)xt;
#pragma unroll 4
        for (int t = 0; t < 32; ++t) {
            int byte = t * 2048 + ((n0 * 2) ^ ((t & 7) << 4));
            bf16x4 v = *(const bf16x4*)(p + byte);
            float s = simv[t];
            a0 += s * (float)v[0];
            a1 += s * (float)v[1];
            a2 += s * (float)v[2];
            a3 += s * (float)v[3];
        }
        float4 o; o.x = a0; o.y = a1; o.z = a2; o.w = a3;
        ((float4*)(outp + (size_t)bs * 1024))[tid] = o;
    }
}

// ---- out[b][j] = sum over NT tile partials ----
template <int NT>
__global__ void k_outred(const float* __restrict__ outp, float* __restrict__ out) {
    const int b = blockIdx.y, j = blockIdx.x * 256 + threadIdx.x;
    const float* p = outp + (size_t)b * NT * 1024 + j;
    float s = 0.f;
    for (int t = 0; t < NT; ++t) s += p[t * 1024];
    out[b * 1024 + j] = s;
}

extern "C" void kernel_launch(void* const* d_in, const int* in_sizes, int n_in,
                              void* d_out, int out_size, void* d_ws, size_t ws_size,
                              hipStream_t stream) {
    const float* x = (const float*)d_in[0];  // [16][4096][1024]
    const float* A = (const float*)d_in[1];  // [1024][1024]
    const float* B = (const float*)d_in[2];  // [1024][1024]
    float* out = (float*)d_out;              // [16][1024] then sim [16][4096]
    float* sim = out + 16 * 1024;
    float* ws = (float*)d_ws;
    float* xs_part = ws;                                  // 524288  (2 MB)
    float* q = ws + 540672;                               // 16384
    float* wv = ws + 557056;                              // 16384
    float* nsq = ws + 573440;                             // 131072 (fallback only)
    float* outp = ws + 704512;                            // up to 8 MB
    unsigned short* Bb = (unsigned short*)(ws + 2801664); // 1M bf16 (2 MB)
    unsigned short* xbf = (unsigned short*)(ws + 3325952);// 64M bf16 (128 MB, optional)
    const bool xb = ws_size >= (size_t)(3325952 + 33554432) * 4;

    if (xb) {
        k_prep<1><<<dim3(32, 16), 256, 0, stream>>>(x, xs_part, xbf);
        k_glue<<<1088, 256, 0, stream>>>(B, Bb, xs_part, A, q);
        k_wf<<<dim3(4, 16), 256, 0, stream>>>(B, q, wv);
        k_main2<<<256, 512, 0, stream>>>(xbf, Bb, wv, outp, sim);
        k_outred<16><<<dim3(4, 16), 256, 0, stream>>>(outp, out);
    } else {
        k_prep<0><<<dim3(32, 16), 256, 0, stream>>>(x, xs_part, (unsigned short*)0);
        k_glue<<<1088, 256, 0, stream>>>(B, Bb, xs_part, A, q);
        k_wf<<<dim3(4, 16), 256, 0, stream>>>(B, q, wv);
        k_nsq_f32<<<dim3(512, 2), 256, 0, stream>>>(x, Bb, nsq);
        k_finish0<<<2048, 256, 0, stream>>>(x, wv, nsq, outp, sim);
        k_outred<128><<<dim3(4, 16), 256, 0, stream>>>(outp, out);
    }
}

// Round 12
// 286.476 us; speedup vs baseline: 1.2024x; 1.0530x over previous
//
#include <hip/hip_runtime.h>

#define EPS 1e-5f

typedef __bf16 bf16x8 __attribute__((ext_vector_type(8)));
typedef __bf16 bf16x4 __attribute__((ext_vector_type(4)));
typedef __bf16 bf16x2 __attribute__((ext_vector_type(2)));
typedef float f32x4 __attribute__((ext_vector_type(4)));

static __device__ __forceinline__ unsigned int f2bf(float f) {
    unsigned int u = __builtin_bit_cast(unsigned int, f);
    u = (u + 0x7fffu + ((u >> 16) & 1u)) >> 16;
    return u;
}

// async global->LDS, 16B per lane. LDS dest is wave-uniform base (+lane*16 by HW).
static __device__ __forceinline__ void gll16(const void* g, void* l) {
    __builtin_amdgcn_global_load_lds(
        (const __attribute__((address_space(1))) unsigned int*)(unsigned long long)g,
        (__attribute__((address_space(3))) unsigned int*)(unsigned int)(unsigned long long)l,
        16, 0, 0);
}

// ---- pass 1: colsum partials (+ optional bf16 copy of x) ----
template <int XBF>
__global__ __launch_bounds__(256) void k_prep(const float* __restrict__ x,
                                              float* __restrict__ xs_part,
                                              unsigned short* __restrict__ xbf) {
    const int b = blockIdx.y, sc = blockIdx.x, tid = threadIdx.x;
    const size_t rowbase = ((size_t)(b * 4096 + sc * 128)) * 1024;
    const float4* src = (const float4*)(x + rowbase) + tid;
    uint2* dst = XBF ? ((uint2*)(xbf + rowbase) + tid) : (uint2*)0;
    float ax = 0.f, ay = 0.f, az = 0.f, aw = 0.f;
    for (int r = 0; r < 128; ++r) {
        float4 v = src[r * 256];
        ax += v.x; ay += v.y; az += v.z; aw += v.w;
        if (XBF) {
            uint2 p;
            p.x = f2bf(v.x) | (f2bf(v.y) << 16);
            p.y = f2bf(v.z) | (f2bf(v.w) << 16);
            dst[r * 256] = p;
        }
    }
    float4 o; o.x = ax; o.y = ay; o.z = az; o.w = aw;
    ((float4*)(xs_part + ((size_t)(b * 32 + sc)) * 1024))[tid] = o;
}

// ---- merged: B->bf16 convert (blocks 0..1023) + xsred+query (blocks 1024..1087) ----
__global__ __launch_bounds__(256) void k_glue(const float* __restrict__ B,
                                              unsigned short* __restrict__ Bb,
                                              const float* __restrict__ xs_part,
                                              const float* __restrict__ A,
                                              float* __restrict__ q) {
    __shared__ float xsl[1024];
    const int blk = blockIdx.x, tid = threadIdx.x;
    if (blk < 1024) {
        const int i = blk * 256 + tid;
        float4 v = ((const float4*)B)[i];
        uint2 p;
        p.x = f2bf(v.x) | (f2bf(v.y) << 16);
        p.y = f2bf(v.z) | (f2bf(v.w) << 16);
        ((uint2*)Bb)[i] = p;
        return;
    }
    const int gb = blk - 1024;
    const int g = gb & 3, b = gb >> 2;
    {
        float4 s4 = {0.f, 0.f, 0.f, 0.f};
        const float4* p = (const float4*)(xs_part + (size_t)b * 32768) + tid;
        for (int sc = 0; sc < 32; ++sc) {
            float4 v = p[sc * 256];
            s4.x += v.x; s4.y += v.y; s4.z += v.z; s4.w += v.w;
        }
        ((float4*)xsl)[tid] = s4;
    }
    __syncthreads();
    const int i = g * 256 + tid;
    const float4* ar = (const float4*)(A + (size_t)i * 1024);
    float acc = 0.f;
    for (int k = 0; k < 256; ++k) {
        float4 a = ar[k], v = ((const float4*)xsl)[k];
        acc += a.x * v.x + a.y * v.y + a.z * v.z + a.w * v.w;
    }
    q[b * 1024 + i] = acc;
}

// ---- fused qnorm + w, high-occupancy: grid (16 jg, 16 b), 256 threads ----
// Each block: 64 columns x full i-range; 4 threads per column (ip = i-quarter).
// w[b,j] = sum_i B[i,j] * (q[b,i]/||q[b]||)
__global__ __launch_bounds__(256) void k_wf(const float* __restrict__ B,
                                            const float* __restrict__ q,
                                            float* __restrict__ w) {
    __shared__ float ql[1024];
    __shared__ float wsum[4];
    __shared__ float part[4][64];
    const int b = blockIdx.y, g = blockIdx.x, tid = threadIdx.x;
    float4 v = ((const float4*)(q + (size_t)b * 1024))[tid];
    float ss = v.x * v.x + v.y * v.y + v.z * v.z + v.w * v.w;
    for (int o = 1; o < 64; o <<= 1) ss += __shfl_xor(ss, o);
    if ((tid & 63) == 0) wsum[tid >> 6] = ss;
    __syncthreads();
    const float inv = 1.f / (EPS + sqrtf(wsum[0] + wsum[1] + wsum[2] + wsum[3]));
    float4 n; n.x = v.x * inv; n.y = v.y * inv; n.z = v.z * inv; n.w = v.w * inv;
    ((float4*)ql)[tid] = n;
    __syncthreads();
    const int jl = tid & 63, ip = tid >> 6;   // wave = one i-quarter; 64 consecutive j
    const int j = g * 64 + jl;
    const float* Bp = B + (size_t)(ip * 256) * 1024 + j;
    const float* qp = ql + ip * 256;
    float acc = 0.f;
#pragma unroll 8
    for (int i = 0; i < 256; ++i) acc += Bp[(size_t)i * 1024] * qp[i];
    part[ip][jl] = acc;
    __syncthreads();
    if (tid < 64)
        w[(size_t)b * 1024 + g * 64 + tid] =
            part[0][tid] + part[1][tid] + part[2][tid] + part[3][tid];
}

#define FENCE asm volatile("" ::: "memory")

// ---- fused main (r4-proven): nsq GEMM (coarse counted-vmcnt) + pipelined finish ----
// grid = 256 blocks (1/CU), 512 threads (8 waves, 2M x 4N over 256x256 sub-tile).
__global__ __launch_bounds__(512, 2) void k_main2(const unsigned short* __restrict__ xbf,
                                                  const unsigned short* __restrict__ Bb,
                                                  const float* __restrict__ w,
                                                  float* __restrict__ outp,
                                                  float* __restrict__ sim_out) {
    __shared__ __align__(16) union {
        struct { unsigned short Xs[2][256 * 64]; unsigned short Bs[2][256 * 64]; } g;
        unsigned short xt2[2][32 * 1024];  // finish double buffer (2 x 64 KB)
    } S;
    __shared__ float nsq_s[256];
    __shared__ float wlds[1024];
    __shared__ float numer_s[32];
    __shared__ float simv[32];

    const int tid = threadIdx.x;
    const int lane = tid & 63;
    const int l15 = lane & 15, lg = lane >> 4;
    const int w8 = tid >> 6;
    const int wm = w8 >> 2, wn = w8 & 3;
    const int bx = blockIdx.x;
    const size_t tok0 = (size_t)bx * 256;
    const int b = bx >> 4;

    ((float2*)wlds)[tid] = ((const float2*)(w + (size_t)b * 1024))[tid];
    if (tid < 256) nsq_s[tid] = 0.f;
    __syncthreads();  // init visible before any use

    // stage step s (mt=s>>4, ks=s&15) into buffer buf: 8 gll16/thread, linear
    // LDS dest, pre-swizzled source chunk c^(row&7) (both-sides-or-neither).
#define STAGE(s_, buf_)                                                                  \
    do {                                                                                 \
        const int mt_ = (s_) >> 4, ks_ = (s_) & 15;                                      \
        _Pragma("unroll") for (int it = 0; it < 4; ++it) {                               \
            const int g_ = it * 512 + tid;                                               \
            const int row_ = g_ >> 3, c_ = g_ & 7;                                       \
            const int csw_ = (c_ ^ (row_ & 7)) * 8;                                      \
            gll16(xbf + (tok0 + row_) * 1024 + ks_ * 64 + csw_,                          \
                  (char*)S.g.Xs[buf_] + (size_t)(it * 512 + (tid & ~63)) * 16);          \
            gll16(Bb + (size_t)(mt_ * 256 + row_) * 1024 + ks_ * 64 + csw_,              \
                  (char*)S.g.Bs[buf_] + (size_t)(it * 512 + (tid & ~63)) * 16);          \
        }                                                                                \
    } while (0)

    f32x4 acc[8][4];

    STAGE(0, 0);
    STAGE(1, 1);

    for (int s = 0; s < 64; ++s) {
        const int buf = s & 1;
        if ((s & 15) == 0) {
#pragma unroll
            for (int mi = 0; mi < 8; ++mi)
#pragma unroll
                for (int ni = 0; ni < 4; ++ni) acc[mi][ni] = (f32x4){0.f, 0.f, 0.f, 0.f};
        }
        // leading sync: drain this step's 8 loads (next step's 8 stay in flight)
        if (s < 62) asm volatile("s_waitcnt vmcnt(8)" ::: "memory");
        else        asm volatile("s_waitcnt vmcnt(0)" ::: "memory");
        __builtin_amdgcn_s_barrier();

        const char* xb = (const char*)S.g.Xs[buf] + (wm * 128 + l15) * 128;
        const char* bb = (const char*)S.g.Bs[buf] + (wn * 64 + l15) * 128;
        const int sw = (l15 & 7) << 4;

        bf16x8 bq[4][2];
#pragma unroll
        for (int ni = 0; ni < 4; ++ni)
#pragma unroll
            for (int kk = 0; kk < 2; ++kk)
                bq[ni][kk] = *(const bf16x8*)(bb + ni * 16 * 128 + ((kk * 64 + lg * 16) ^ sw));

        __builtin_amdgcn_s_setprio(1);
#pragma unroll
        for (int p = 0; p < 4; ++p) {
            bf16x8 a[2][2];
#pragma unroll
            for (int mi = 0; mi < 2; ++mi)
#pragma unroll
                for (int kk = 0; kk < 2; ++kk)
                    a[mi][kk] = *(const bf16x8*)(xb + (p * 2 + mi) * 16 * 128 +
                                                 ((kk * 64 + lg * 16) ^ sw));
#pragma unroll
            for (int mi = 0; mi < 2; ++mi)
#pragma unroll
                for (int ni = 0; ni < 4; ++ni)
#pragma unroll
                    for (int kk = 0; kk < 2; ++kk)
                        acc[p * 2 + mi][ni] = __builtin_amdgcn_mfma_f32_16x16x32_bf16(
                            a[mi][kk], bq[ni][kk], acc[p * 2 + mi][ni], 0, 0, 0);
        }
        __builtin_amdgcn_s_setprio(0);

        FENCE;
        __builtin_amdgcn_s_barrier();  // all waves done reading buf; safe to overwrite
        FENCE;
        if (s + 2 < 64) STAGE(s + 2, buf);

        if ((s & 15) == 15) {  // end of m-tile: fold squares, reduce, LDS-atomic
#pragma unroll
            for (int mi = 0; mi < 8; ++mi)
#pragma unroll
                for (int r = 0; r < 4; ++r) {
                    float v = 0.f;
#pragma unroll
                    for (int ni = 0; ni < 4; ++ni) v += acc[mi][ni][r] * acc[mi][ni][r];
                    v += __shfl_xor(v, 1);
                    v += __shfl_xor(v, 2);
                    v += __shfl_xor(v, 4);
                    v += __shfl_xor(v, 8);
                    if (l15 == 0) atomicAdd(&nsq_s[wm * 128 + mi * 16 + lg * 4 + r], v);
                }
        }
    }
#undef STAGE

    // ---- pipelined finish: per 32-token sub-tile: numer, sim, out-partial ----
    // sub-tile = 32 tok x 1024 cols bf16 = 64 KB; double-buffered in the union.
#define STAGE_SUB(sub_, bf_)                                                             \
    do {                                                                                 \
        _Pragma("unroll") for (int it = 0; it < 8; ++it) {                               \
            const int idx_ = it * 512 + tid;                                             \
            const int row_ = idx_ >> 7, c_ = idx_ & 127;                                 \
            gll16(xbf + (tok0 + (sub_) * 32 + row_) * 1024 + ((c_ ^ (row_ & 7)) * 8),    \
                  (char*)S.xt2[bf_] + (size_t)(it * 512 + (tid & ~63)) * 16);            \
        }                                                                                \
    } while (0)

    // GEMM loop ended with a trailing barrier (and vmcnt(0) at s=62/63): union is
    // free. Issue sub-0 stage now so it overlaps the nsq visibility sync below.
    STAGE_SUB(0, 0);
    asm volatile("s_waitcnt lgkmcnt(0)" ::: "memory");
    __builtin_amdgcn_s_barrier();  // nsq_s atomics visible to all waves

    float oa0 = 0.f, oa1 = 0.f;
    for (int sub = 0; sub < 8; ++sub) {
        const int cur = sub & 1;
        if (sub < 7) STAGE_SUB(sub + 1, cur ^ 1);  // issue next before waiting on cur
        if (sub < 7) asm volatile("s_waitcnt vmcnt(8)" ::: "memory");
        else         asm volatile("s_waitcnt vmcnt(0)" ::: "memory");
        __builtin_amdgcn_s_barrier();  // cur buffer fully staged

        const char* xt = (const char*)S.xt2[cur];
        {   // numer: 16 lanes per token
            const int t = tid >> 4, kp = tid & 15;
            const char* pt = xt + t * 2048;
            const int sw2 = (t & 7) << 4;
            float acc2 = 0.f;
#pragma unroll
            for (int j = 0; j < 8; ++j) {
                bf16x8 v = *(const bf16x8*)(pt + ((j * 256 + kp * 16) ^ sw2));
                const float* wp = wlds + j * 128 + kp * 8;
#pragma unroll
                for (int e = 0; e < 8; ++e) acc2 += (float)v[e] * wp[e];
            }
            acc2 += __shfl_xor(acc2, 1);
            acc2 += __shfl_xor(acc2, 2);
            acc2 += __shfl_xor(acc2, 4);
            acc2 += __shfl_xor(acc2, 8);
            if (kp == 0) numer_s[t] = acc2;
        }
        asm volatile("s_waitcnt lgkmcnt(0)" ::: "memory");
        __builtin_amdgcn_s_barrier();

        if (tid < 32) {
            float sv = numer_s[tid] / (EPS + sqrtf(nsq_s[sub * 32 + tid]));
            simv[tid] = sv;
            sim_out[tok0 + sub * 32 + tid] = sv;
        }
        asm volatile("s_waitcnt lgkmcnt(0)" ::: "memory");
        __builtin_amdgcn_s_barrier();

        {   // out partial: each lane owns 2 columns
            const int nb = tid * 4;
#pragma unroll 4
            for (int t = 0; t < 32; ++t) {
                bf16x2 v = *(const bf16x2*)(xt + t * 2048 + (nb ^ ((t & 7) << 4)));
                float sv = simv[t];
                oa0 += sv * (float)v[0];
                oa1 += sv * (float)v[1];
            }
        }
        asm volatile("s_waitcnt lgkmcnt(0)" ::: "memory");
        __builtin_amdgcn_s_barrier();  // cur reads retired; next stage may overwrite
    }
#undef STAGE_SUB
    float2 o; o.x = oa0; o.y = oa1;
    ((float2*)(outp + (size_t)bx * 1024))[tid] = o;
}

// ---- fallback pass 3 (no xbf workspace): 128x128 tile from f32 x ----
__global__ __launch_bounds__(256, 2) void k_nsq_f32(const float* __restrict__ x,
                                                    const unsigned short* __restrict__ Bb,
                                                    float* __restrict__ nsq_g) {
    __shared__ unsigned short Xs[128 * 64];
    __shared__ unsigned short Bs[128 * 64];
    __shared__ float nsq_s[128];

    const int tid = threadIdx.x;
    const int lane = tid & 63;
    const int l15 = lane & 15, lg = lane >> 4;
    const int w = tid >> 6;
    const int wr = w >> 1, wc = w & 1;
    const int st = blockIdx.x * 128;
    const int mh = blockIdx.y;

    float nsq_reg[4][4];
#pragma unroll
    for (int mi = 0; mi < 4; ++mi)
#pragma unroll
        for (int r = 0; r < 4; ++r) nsq_reg[mi][r] = 0.f;

    for (int mti = 0; mti < 4; ++mti) {
        const int mt = mh * 4 + mti;
        f32x4 acc[4][4];
#pragma unroll
        for (int mi = 0; mi < 4; ++mi)
#pragma unroll
            for (int ni = 0; ni < 4; ++ni) acc[mi][ni] = (f32x4){0.f, 0.f, 0.f, 0.f};

        for (int ks = 0; ks < 16; ++ks) {
            __syncthreads();
            {
                const int row = tid >> 1, kh = tid & 1;
                const float* srcx = x + (size_t)(st + row) * 1024 + ks * 64 + kh * 32;
                char* ldsrow = (char*)Xs + row * 128;
                const int sw = (row & 7) << 4;
#pragma unroll
                for (int j = 0; j < 4; ++j) {
                    float4 v0 = ((const float4*)srcx)[j * 2];
                    float4 v1 = ((const float4*)srcx)[j * 2 + 1];
                    uint4 p;
                    p.x = f2bf(v0.x) | (f2bf(v0.y) << 16);
                    p.y = f2bf(v0.z) | (f2bf(v0.w) << 16);
                    p.z = f2bf(v1.x) | (f2bf(v1.y) << 16);
                    p.w = f2bf(v1.z) | (f2bf(v1.w) << 16);
                    *(uint4*)(ldsrow + (((kh * 4 + j) * 16) ^ sw)) = p;
                }
#pragma unroll
                for (int it = 0; it < 4; ++it) {
                    const int idx = it * 256 + tid;
                    const int brow = idx >> 3, c = idx & 7;
                    char* baseB = (char*)Bs + (size_t)(it * 256 + (tid & ~63)) * 16;
                    gll16(Bb + (size_t)(mt * 128 + brow) * 1024 + ks * 64 + (c ^ (brow & 7)) * 8,
                          baseB);
                }
            }
            __syncthreads();

            const char* xb = (const char*)Xs + (wr * 64 + l15) * 128;
            const char* bb = (const char*)Bs + (wc * 64 + l15) * 128;
            const int sw = (l15 & 7) << 4;
#pragma unroll
            for (int kk = 0; kk < 2; ++kk) {
                const int ob = (kk * 64 + lg * 16) ^ sw;
                bf16x8 a[4], bq[4];
#pragma unroll
                for (int mi = 0; mi < 4; ++mi) a[mi] = *(const bf16x8*)(xb + mi * 2048 + ob);
#pragma unroll
                for (int ni = 0; ni < 4; ++ni) bq[ni] = *(const bf16x8*)(bb + ni * 2048 + ob);
#pragma unroll
                for (int mi = 0; mi < 4; ++mi)
#pragma unroll
                    for (int ni = 0; ni < 4; ++ni)
                        acc[mi][ni] = __builtin_amdgcn_mfma_f32_16x16x32_bf16(
                            a[mi], bq[ni], acc[mi][ni], 0, 0, 0);
            }
        }
#pragma unroll
        for (int mi = 0; mi < 4; ++mi)
#pragma unroll
            for (int ni = 0; ni < 4; ++ni)
#pragma unroll
                for (int r = 0; r < 4; ++r)
                    nsq_reg[mi][r] += acc[mi][ni][r] * acc[mi][ni][r];
    }

    if (tid < 128) nsq_s[tid] = 0.f;
    __syncthreads();
#pragma unroll
    for (int mi = 0; mi < 4; ++mi)
#pragma unroll
        for (int r = 0; r < 4; ++r) {
            float v = nsq_reg[mi][r];
            v += __shfl_xor(v, 1);
            v += __shfl_xor(v, 2);
            v += __shfl_xor(v, 4);
            v += __shfl_xor(v, 8);
            if (l15 == 0) atomicAdd(&nsq_s[wr * 64 + mi * 16 + lg * 4 + r], v);
        }
    __syncthreads();
    if (tid < 128) nsq_g[(size_t)mh * 65536 + st + tid] = nsq_s[tid];
}

// ---- fallback pass 4 ----
__global__ __launch_bounds__(256, 2) void k_finish0(
    const float* __restrict__ x, const float* __restrict__ w,
    const float* __restrict__ nsq_g, float* __restrict__ outp,
    float* __restrict__ sim_out) {
    __shared__ __align__(16) unsigned short xt[32 * 1024];
    __shared__ float numer[32];
    __shared__ float simv[32];

    const int tid = threadIdx.x;
    const int bs = blockIdx.x;
    const int b = bs >> 7, s0 = (bs & 127) * 32;
    const size_t tok0 = (size_t)b * 4096 + s0;

    const float4* src = (const float4*)(x + tok0 * 1024) + tid;
    char* lds = (char*)xt;
    for (int r = 0; r < 32; ++r) {
        float4 v = src[r * 256];
        uint2 p;
        p.x = f2bf(v.x) | (f2bf(v.y) << 16);
        p.y = f2bf(v.z) | (f2bf(v.w) << 16);
        *(uint2*)(lds + r * 2048 + ((tid * 8) ^ ((r & 7) << 4))) = p;
    }
    __syncthreads();

    {
        const int t = tid >> 3, kp = tid & 7;
        const float* wb = w + (size_t)b * 1024 + kp * 128;
        const char* pt = (const char*)xt + t * 2048;
        const int sw2 = (t & 7) << 4;
        float acc = 0.f;
#pragma unroll
        for (int j = 0; j < 16; ++j) {
            const int kb = (kp * 128 + j * 8) * 2;
            bf16x8 v = *(const bf16x8*)(pt + (kb ^ sw2));
#pragma unroll
            for (int e = 0; e < 8; ++e) acc += (float)v[e] * wb[j * 8 + e];
        }
        acc += __shfl_xor(acc, 1);
        acc += __shfl_xor(acc, 2);
        acc += __shfl_xor(acc, 4);
        if (kp == 0) numer[t] = acc;
    }
    __syncthreads();

    if (tid < 32) {
        float nt = nsq_g[tok0 + tid] + nsq_g[65536 + tok0 + tid];
        float s = numer[tid] / (EPS + sqrtf(nt));
        simv[tid] = s;
        sim_out[tok0 + tid] = s;
    }
    __syncthreads();

    {
        const int n0 = tid * 4;
        float a0 = 0.f, a1 = 0.f, a2 = 0.f, a3 = 0.f;
        const char* p = (const char*)xt;
#pragma unroll 4
        for (int t = 0; t < 32; ++t) {
            int byte = t * 2048 + ((n0 * 2) ^ ((t & 7) << 4));
            bf16x4 v = *(const bf16x4*)(p + byte);
            float s = simv[t];
            a0 += s * (float)v[0];
            a1 += s * (float)v[1];
            a2 += s * (float)v[2];
            a3 += s * (float)v[3];
        }
        float4 o; o.x = a0; o.y = a1; o.z = a2; o.w = a3;
        ((float4*)(outp + (size_t)bs * 1024))[tid] = o;
    }
}

// ---- out[b][j] = sum over NT tile partials ----
template <int NT>
__global__ void k_outred(const float* __restrict__ outp, float* __restrict__ out) {
    const int b = blockIdx.y, j = blockIdx.x * 256 + threadIdx.x;
    const float* p = outp + (size_t)b * NT * 1024 + j;
    float s = 0.f;
    for (int t = 0; t < NT; ++t) s += p[t * 1024];
    out[b * 1024 + j] = s;
}

extern "C" void kernel_launch(void* const* d_in, const int* in_sizes, int n_in,
                              void* d_out, int out_size, void* d_ws, size_t ws_size,
                              hipStream_t stream) {
    const float* x = (const float*)d_in[0];  // [16][4096][1024]
    const float* A = (const float*)d_in[1];  // [1024][1024]
    const float* B = (const float*)d_in[2];  // [1024][1024]
    float* out = (float*)d_out;              // [16][1024] then sim [16][4096]
    float* sim = out + 16 * 1024;
    float* ws = (float*)d_ws;
    float* xs_part = ws;                                  // 524288  (2 MB)
    float* q = ws + 540672;                               // 16384
    float* wv = ws + 557056;                              // 16384
    float* nsq = ws + 573440;                             // 131072 (fallback only)
    float* outp = ws + 704512;                            // up to 8 MB
    unsigned short* Bb = (unsigned short*)(ws + 2801664); // 1M bf16 (2 MB)
    unsigned short* xbf = (unsigned short*)(ws + 3325952);// 64M bf16 (128 MB, optional)
    const bool xb = ws_size >= (size_t)(3325952 + 33554432) * 4;

    if (xb) {
        k_prep<1><<<dim3(32, 16), 256, 0, stream>>>(x, xs_part, xbf);
        k_glue<<<1088, 256, 0, stream>>>(B, Bb, xs_part, A, q);
        k_wf<<<dim3(16, 16), 256, 0, stream>>>(B, q, wv);
        k_main2<<<256, 512, 0, stream>>>(xbf, Bb, wv, outp, sim);
        k_outred<16><<<dim3(4, 16), 256, 0, stream>>>(outp, out);
    } else {
        k_prep<0><<<dim3(32, 16), 256, 0, stream>>>(x, xs_part, (unsigned short*)0);
        k_glue<<<1088, 256, 0, stream>>>(B, Bb, xs_part, A, q);
        k_wf<<<dim3(16, 16), 256, 0, stream>>>(B, q, wv);
        k_nsq_f32<<<dim3(512, 2), 256, 0, stream>>>(x, Bb, nsq);
        k_finish0<<<2048, 256, 0, stream>>>(x, wv, nsq, outp, sim);
        k_outred<128><<<dim3(4, 16), 256, 0, stream>>>(outp, out);
    }
}

// Round 13
// 265.368 us; speedup vs baseline: 1.2980x; 1.0795x over previous
//
#include <hip/hip_runtime.h>

#define EPS 1e-5f

typedef __bf16 bf16x8 __attribute__((ext_vector_type(8)));
typedef __bf16 bf16x4 __attribute__((ext_vector_type(4)));
typedef __bf16 bf16x2 __attribute__((ext_vector_type(2)));
typedef float f32x4 __attribute__((ext_vector_type(4)));

static __device__ __forceinline__ unsigned int f2bf(float f) {
    unsigned int u = __builtin_bit_cast(unsigned int, f);
    u = (u + 0x7fffu + ((u >> 16) & 1u)) >> 16;
    return u;
}

// async global->LDS, 16B per lane. LDS dest is wave-uniform base (+lane*16 by HW).
static __device__ __forceinline__ void gll16(const void* g, void* l) {
    __builtin_amdgcn_global_load_lds(
        (const __attribute__((address_space(1))) unsigned int*)(unsigned long long)g,
        (__attribute__((address_space(3))) unsigned int*)(unsigned int)(unsigned long long)l,
        16, 0, 0);
}

// ---- pass 1: colsum partials (+ optional bf16 copy of x) ----
template <int XBF>
__global__ __launch_bounds__(256) void k_prep(const float* __restrict__ x,
                                              float* __restrict__ xs_part,
                                              unsigned short* __restrict__ xbf) {
    const int b = blockIdx.y, sc = blockIdx.x, tid = threadIdx.x;
    const size_t rowbase = ((size_t)(b * 4096 + sc * 128)) * 1024;
    const float4* src = (const float4*)(x + rowbase) + tid;
    uint2* dst = XBF ? ((uint2*)(xbf + rowbase) + tid) : (uint2*)0;
    float ax = 0.f, ay = 0.f, az = 0.f, aw = 0.f;
    for (int r = 0; r < 128; ++r) {
        float4 v = src[r * 256];
        ax += v.x; ay += v.y; az += v.z; aw += v.w;
        if (XBF) {
            uint2 p;
            p.x = f2bf(v.x) | (f2bf(v.y) << 16);
            p.y = f2bf(v.z) | (f2bf(v.w) << 16);
            dst[r * 256] = p;
        }
    }
    float4 o; o.x = ax; o.y = ay; o.z = az; o.w = aw;
    ((float4*)(xs_part + ((size_t)(b * 32 + sc)) * 1024))[tid] = o;
}

// ---- merged: B->bf16 convert (blocks 0..1023) + xsred+query (blocks 1024..1279) ----
// query half: 16 blocks per batch; block covers 64 outputs, 4 threads/output
// (ip = k-quarter) -> 64 serial iterations instead of 256.
__global__ __launch_bounds__(256) void k_glue(const float* __restrict__ B,
                                              unsigned short* __restrict__ Bb,
                                              const float* __restrict__ xs_part,
                                              const float* __restrict__ A,
                                              float* __restrict__ q) {
    __shared__ float xsl[1024];
    __shared__ float part[4][64];
    const int blk = blockIdx.x, tid = threadIdx.x;
    if (blk < 1024) {
        const int i = blk * 256 + tid;
        float4 v = ((const float4*)B)[i];
        uint2 p;
        p.x = f2bf(v.x) | (f2bf(v.y) << 16);
        p.y = f2bf(v.z) | (f2bf(v.w) << 16);
        ((uint2*)Bb)[i] = p;
        return;
    }
    const int qb = blk - 1024;
    const int b = qb >> 4, g = qb & 15;
    {
        float4 s4 = {0.f, 0.f, 0.f, 0.f};
        const float4* p = (const float4*)(xs_part + (size_t)b * 32768) + tid;
        for (int sc = 0; sc < 32; ++sc) {
            float4 v = p[sc * 256];
            s4.x += v.x; s4.y += v.y; s4.z += v.z; s4.w += v.w;
        }
        ((float4*)xsl)[tid] = s4;
    }
    __syncthreads();
    const int jl = tid & 63, ip = tid >> 6;
    const int i = g * 64 + jl;
    const float4* ar = (const float4*)(A + (size_t)i * 1024) + ip * 64;
    const float4* xr = (const float4*)xsl + ip * 64;
    float acc = 0.f;
#pragma unroll 8
    for (int k = 0; k < 64; ++k) {
        float4 a = ar[k], v = xr[k];
        acc += a.x * v.x + a.y * v.y + a.z * v.z + a.w * v.w;
    }
    part[ip][jl] = acc;
    __syncthreads();
    if (tid < 64)
        q[(size_t)b * 1024 + g * 64 + tid] =
            part[0][tid] + part[1][tid] + part[2][tid] + part[3][tid];
}

// ---- fused qnorm + w, high-occupancy: grid (16 jg, 16 b), 256 threads ----
// Each block: 64 columns x full i-range; 4 threads per column (ip = i-quarter).
// w[b,j] = sum_i B[i,j] * (q[b,i]/||q[b]||)
__global__ __launch_bounds__(256) void k_wf(const float* __restrict__ B,
                                            const float* __restrict__ q,
                                            float* __restrict__ w) {
    __shared__ float ql[1024];
    __shared__ float wsum[4];
    __shared__ float part[4][64];
    const int b = blockIdx.y, g = blockIdx.x, tid = threadIdx.x;
    float4 v = ((const float4*)(q + (size_t)b * 1024))[tid];
    float ss = v.x * v.x + v.y * v.y + v.z * v.z + v.w * v.w;
    for (int o = 1; o < 64; o <<= 1) ss += __shfl_xor(ss, o);
    if ((tid & 63) == 0) wsum[tid >> 6] = ss;
    __syncthreads();
    const float inv = 1.f / (EPS + sqrtf(wsum[0] + wsum[1] + wsum[2] + wsum[3]));
    float4 n; n.x = v.x * inv; n.y = v.y * inv; n.z = v.z * inv; n.w = v.w * inv;
    ((float4*)ql)[tid] = n;
    __syncthreads();
    const int jl = tid & 63, ip = tid >> 6;   // wave = one i-quarter; 64 consecutive j
    const int j = g * 64 + jl;
    const float* Bp = B + (size_t)(ip * 256) * 1024 + j;
    const float* qp = ql + ip * 256;
    float acc = 0.f;
#pragma unroll 8
    for (int i = 0; i < 256; ++i) acc += Bp[(size_t)i * 1024] * qp[i];
    part[ip][jl] = acc;
    __syncthreads();
    if (tid < 64)
        w[(size_t)b * 1024 + g * 64 + tid] =
            part[0][tid] + part[1][tid] + part[2][tid] + part[3][tid];
}

#define FENCE asm volatile("" ::: "memory")

// ---- fused main (r4-proven): nsq GEMM (coarse counted-vmcnt) + pipelined finish ----
// grid = 256 blocks (1/CU), 512 threads (8 waves, 2M x 4N over 256x256 sub-tile).
__global__ __launch_bounds__(512, 2) void k_main2(const unsigned short* __restrict__ xbf,
                                                  const unsigned short* __restrict__ Bb,
                                                  const float* __restrict__ w,
                                                  float* __restrict__ outp,
                                                  float* __restrict__ sim_out) {
    __shared__ __align__(16) union {
        struct { unsigned short Xs[2][256 * 64]; unsigned short Bs[2][256 * 64]; } g;
        unsigned short xt2[2][32 * 1024];  // finish double buffer (2 x 64 KB)
    } S;
    __shared__ float nsq_s[256];
    __shared__ float wlds[1024];
    __shared__ float numer_s[32];
    __shared__ float simv[32];

    const int tid = threadIdx.x;
    const int lane = tid & 63;
    const int l15 = lane & 15, lg = lane >> 4;
    const int w8 = tid >> 6;
    const int wm = w8 >> 2, wn = w8 & 3;
    const int bx = blockIdx.x;
    const size_t tok0 = (size_t)bx * 256;
    const int b = bx >> 4;

    ((float2*)wlds)[tid] = ((const float2*)(w + (size_t)b * 1024))[tid];
    if (tid < 256) nsq_s[tid] = 0.f;
    __syncthreads();  // init visible before any use

    // stage step s (mt=s>>4, ks=s&15) into buffer buf: 8 gll16/thread, linear
    // LDS dest, pre-swizzled source chunk c^(row&7) (both-sides-or-neither).
#define STAGE(s_, buf_)                                                                  \
    do {                                                                                 \
        const int mt_ = (s_) >> 4, ks_ = (s_) & 15;                                      \
        _Pragma("unroll") for (int it = 0; it < 4; ++it) {                               \
            const int g_ = it * 512 + tid;                                               \
            const int row_ = g_ >> 3, c_ = g_ & 7;                                       \
            const int csw_ = (c_ ^ (row_ & 7)) * 8;                                      \
            gll16(xbf + (tok0 + row_) * 1024 + ks_ * 64 + csw_,                          \
                  (char*)S.g.Xs[buf_] + (size_t)(it * 512 + (tid & ~63)) * 16);          \
            gll16(Bb + (size_t)(mt_ * 256 + row_) * 1024 + ks_ * 64 + csw_,              \
                  (char*)S.g.Bs[buf_] + (size_t)(it * 512 + (tid & ~63)) * 16);          \
        }                                                                                \
    } while (0)

    f32x4 acc[8][4];

    STAGE(0, 0);
    STAGE(1, 1);

    for (int s = 0; s < 64; ++s) {
        const int buf = s & 1;
        if ((s & 15) == 0) {
#pragma unroll
            for (int mi = 0; mi < 8; ++mi)
#pragma unroll
                for (int ni = 0; ni < 4; ++ni) acc[mi][ni] = (f32x4){0.f, 0.f, 0.f, 0.f};
        }
        // leading sync: drain this step's 8 loads (next step's 8 stay in flight)
        if (s < 62) asm volatile("s_waitcnt vmcnt(8)" ::: "memory");
        else        asm volatile("s_waitcnt vmcnt(0)" ::: "memory");
        __builtin_amdgcn_s_barrier();

        const char* xb = (const char*)S.g.Xs[buf] + (wm * 128 + l15) * 128;
        const char* bb = (const char*)S.g.Bs[buf] + (wn * 64 + l15) * 128;
        const int sw = (l15 & 7) << 4;

        bf16x8 bq[4][2];
#pragma unroll
        for (int ni = 0; ni < 4; ++ni)
#pragma unroll
            for (int kk = 0; kk < 2; ++kk)
                bq[ni][kk] = *(const bf16x8*)(bb + ni * 16 * 128 + ((kk * 64 + lg * 16) ^ sw));

        __builtin_amdgcn_s_setprio(1);
#pragma unroll
        for (int p = 0; p < 4; ++p) {
            bf16x8 a[2][2];
#pragma unroll
            for (int mi = 0; mi < 2; ++mi)
#pragma unroll
                for (int kk = 0; kk < 2; ++kk)
                    a[mi][kk] = *(const bf16x8*)(xb + (p * 2 + mi) * 16 * 128 +
                                                 ((kk * 64 + lg * 16) ^ sw));
#pragma unroll
            for (int mi = 0; mi < 2; ++mi)
#pragma unroll
                for (int ni = 0; ni < 4; ++ni)
#pragma unroll
                    for (int kk = 0; kk < 2; ++kk)
                        acc[p * 2 + mi][ni] = __builtin_amdgcn_mfma_f32_16x16x32_bf16(
                            a[mi][kk], bq[ni][kk], acc[p * 2 + mi][ni], 0, 0, 0);
        }
        __builtin_amdgcn_s_setprio(0);

        FENCE;
        __builtin_amdgcn_s_barrier();  // all waves done reading buf; safe to overwrite
        FENCE;
        if (s + 2 < 64) STAGE(s + 2, buf);

        if ((s & 15) == 15) {  // end of m-tile: fold squares, reduce, LDS-atomic
#pragma unroll
            for (int mi = 0; mi < 8; ++mi)
#pragma unroll
                for (int r = 0; r < 4; ++r) {
                    float v = 0.f;
#pragma unroll
                    for (int ni = 0; ni < 4; ++ni) v += acc[mi][ni][r] * acc[mi][ni][r];
                    v += __shfl_xor(v, 1);
                    v += __shfl_xor(v, 2);
                    v += __shfl_xor(v, 4);
                    v += __shfl_xor(v, 8);
                    if (l15 == 0) atomicAdd(&nsq_s[wm * 128 + mi * 16 + lg * 4 + r], v);
                }
        }
    }
#undef STAGE

    // ---- pipelined finish: per 32-token sub-tile: numer, sim, out-partial ----
    // sub-tile = 32 tok x 1024 cols bf16 = 64 KB; double-buffered in the union.
#define STAGE_SUB(sub_, bf_)                                                             \
    do {                                                                                 \
        _Pragma("unroll") for (int it = 0; it < 8; ++it) {                               \
            const int idx_ = it * 512 + tid;                                             \
            const int row_ = idx_ >> 7, c_ = idx_ & 127;                                 \
            gll16(xbf + (tok0 + (sub_) * 32 + row_) * 1024 + ((c_ ^ (row_ & 7)) * 8),    \
                  (char*)S.xt2[bf_] + (size_t)(it * 512 + (tid & ~63)) * 16);            \
        }                                                                                \
    } while (0)

    // GEMM loop ended with a trailing barrier (and vmcnt(0) at s=62/63): union is
    // free. Issue sub-0 stage now so it overlaps the nsq visibility sync below.
    STAGE_SUB(0, 0);
    asm volatile("s_waitcnt lgkmcnt(0)" ::: "memory");
    __builtin_amdgcn_s_barrier();  // nsq_s atomics visible to all waves

    float oa0 = 0.f, oa1 = 0.f;
    for (int sub = 0; sub < 8; ++sub) {
        const int cur = sub & 1;
        if (sub < 7) STAGE_SUB(sub + 1, cur ^ 1);  // issue next before waiting on cur
        if (sub < 7) asm volatile("s_waitcnt vmcnt(8)" ::: "memory");
        else         asm volatile("s_waitcnt vmcnt(0)" ::: "memory");
        __builtin_amdgcn_s_barrier();  // cur buffer fully staged

        const char* xt = (const char*)S.xt2[cur];
        {   // numer: 16 lanes per token
            const int t = tid >> 4, kp = tid & 15;
            const char* pt = xt + t * 2048;
            const int sw2 = (t & 7) << 4;
            float acc2 = 0.f;
#pragma unroll
            for (int j = 0; j < 8; ++j) {
                bf16x8 v = *(const bf16x8*)(pt + ((j * 256 + kp * 16) ^ sw2));
                const float* wp = wlds + j * 128 + kp * 8;
#pragma unroll
                for (int e = 0; e < 8; ++e) acc2 += (float)v[e] * wp[e];
            }
            acc2 += __shfl_xor(acc2, 1);
            acc2 += __shfl_xor(acc2, 2);
            acc2 += __shfl_xor(acc2, 4);
            acc2 += __shfl_xor(acc2, 8);
            if (kp == 0) numer_s[t] = acc2;
        }
        asm volatile("s_waitcnt lgkmcnt(0)" ::: "memory");
        __builtin_amdgcn_s_barrier();

        if (tid < 32) {
            float sv = numer_s[tid] / (EPS + sqrtf(nsq_s[sub * 32 + tid]));
            simv[tid] = sv;
            sim_out[tok0 + sub * 32 + tid] = sv;
        }
        asm volatile("s_waitcnt lgkmcnt(0)" ::: "memory");
        __builtin_amdgcn_s_barrier();

        {   // out partial: each lane owns 2 columns
            const int nb = tid * 4;
#pragma unroll 4
            for (int t = 0; t < 32; ++t) {
                bf16x2 v = *(const bf16x2*)(xt + t * 2048 + (nb ^ ((t & 7) << 4)));
                float sv = simv[t];
                oa0 += sv * (float)v[0];
                oa1 += sv * (float)v[1];
            }
        }
        asm volatile("s_waitcnt lgkmcnt(0)" ::: "memory");
        __builtin_amdgcn_s_barrier();  // cur reads retired; next stage may overwrite
    }
#undef STAGE_SUB
    float2 o; o.x = oa0; o.y = oa1;
    ((float2*)(outp + (size_t)bx * 1024))[tid] = o;
}

// ---- fallback pass 3 (no xbf workspace): 128x128 tile from f32 x ----
__global__ __launch_bounds__(256, 2) void k_nsq_f32(const float* __restrict__ x,
                                                    const unsigned short* __restrict__ Bb,
                                                    float* __restrict__ nsq_g) {
    __shared__ unsigned short Xs[128 * 64];
    __shared__ unsigned short Bs[128 * 64];
    __shared__ float nsq_s[128];

    const int tid = threadIdx.x;
    const int lane = tid & 63;
    const int l15 = lane & 15, lg = lane >> 4;
    const int w = tid >> 6;
    const int wr = w >> 1, wc = w & 1;
    const int st = blockIdx.x * 128;
    const int mh = blockIdx.y;

    float nsq_reg[4][4];
#pragma unroll
    for (int mi = 0; mi < 4; ++mi)
#pragma unroll
        for (int r = 0; r < 4; ++r) nsq_reg[mi][r] = 0.f;

    for (int mti = 0; mti < 4; ++mti) {
        const int mt = mh * 4 + mti;
        f32x4 acc[4][4];
#pragma unroll
        for (int mi = 0; mi < 4; ++mi)
#pragma unroll
            for (int ni = 0; ni < 4; ++ni) acc[mi][ni] = (f32x4){0.f, 0.f, 0.f, 0.f};

        for (int ks = 0; ks < 16; ++ks) {
            __syncthreads();
            {
                const int row = tid >> 1, kh = tid & 1;
                const float* srcx = x + (size_t)(st + row) * 1024 + ks * 64 + kh * 32;
                char* ldsrow = (char*)Xs + row * 128;
                const int sw = (row & 7) << 4;
#pragma unroll
                for (int j = 0; j < 4; ++j) {
                    float4 v0 = ((const float4*)srcx)[j * 2];
                    float4 v1 = ((const float4*)srcx)[j * 2 + 1];
                    uint4 p;
                    p.x = f2bf(v0.x) | (f2bf(v0.y) << 16);
                    p.y = f2bf(v0.z) | (f2bf(v0.w) << 16);
                    p.z = f2bf(v1.x) | (f2bf(v1.y) << 16);
                    p.w = f2bf(v1.z) | (f2bf(v1.w) << 16);
                    *(uint4*)(ldsrow + (((kh * 4 + j) * 16) ^ sw)) = p;
                }
#pragma unroll
                for (int it = 0; it < 4; ++it) {
                    const int idx = it * 256 + tid;
                    const int brow = idx >> 3, c = idx & 7;
                    char* baseB = (char*)Bs + (size_t)(it * 256 + (tid & ~63)) * 16;
                    gll16(Bb + (size_t)(mt * 128 + brow) * 1024 + ks * 64 + (c ^ (brow & 7)) * 8,
                          baseB);
                }
            }
            __syncthreads();

            const char* xb = (const char*)Xs + (wr * 64 + l15) * 128;
            const char* bb = (const char*)Bs + (wc * 64 + l15) * 128;
            const int sw = (l15 & 7) << 4;
#pragma unroll
            for (int kk = 0; kk < 2; ++kk) {
                const int ob = (kk * 64 + lg * 16) ^ sw;
                bf16x8 a[4], bq[4];
#pragma unroll
                for (int mi = 0; mi < 4; ++mi) a[mi] = *(const bf16x8*)(xb + mi * 2048 + ob);
#pragma unroll
                for (int ni = 0; ni < 4; ++ni) bq[ni] = *(const bf16x8*)(bb + ni * 2048 + ob);
#pragma unroll
                for (int mi = 0; mi < 4; ++mi)
#pragma unroll
                    for (int ni = 0; ni < 4; ++ni)
                        acc[mi][ni] = __builtin_amdgcn_mfma_f32_16x16x32_bf16(
                            a[mi], bq[ni], acc[mi][ni], 0, 0, 0);
            }
        }
#pragma unroll
        for (int mi = 0; mi < 4; ++mi)
#pragma unroll
            for (int ni = 0; ni < 4; ++ni)
#pragma unroll
                for (int r = 0; r < 4; ++r)
                    nsq_reg[mi][r] += acc[mi][ni][r] * acc[mi][ni][r];
    }

    if (tid < 128) nsq_s[tid] = 0.f;
    __syncthreads();
#pragma unroll
    for (int mi = 0; mi < 4; ++mi)
#pragma unroll
        for (int r = 0; r < 4; ++r) {
            float v = nsq_reg[mi][r];
            v += __shfl_xor(v, 1);
            v += __shfl_xor(v, 2);
            v += __shfl_xor(v, 4);
            v += __shfl_xor(v, 8);
            if (l15 == 0) atomicAdd(&nsq_s[wr * 64 + mi * 16 + lg * 4 + r], v);
        }
    __syncthreads();
    if (tid < 128) nsq_g[(size_t)mh * 65536 + st + tid] = nsq_s[tid];
}

// ---- fallback pass 4 ----
__global__ __launch_bounds__(256, 2) void k_finish0(
    const float* __restrict__ x, const float* __restrict__ w,
    const float* __restrict__ nsq_g, float* __restrict__ outp,
    float* __restrict__ sim_out) {
    __shared__ __align__(16) unsigned short xt[32 * 1024];
    __shared__ float numer[32];
    __shared__ float simv[32];

    const int tid = threadIdx.x;
    const int bs = blockIdx.x;
    const int b = bs >> 7, s0 = (bs & 127) * 32;
    const size_t tok0 = (size_t)b * 4096 + s0;

    const float4* src = (const float4*)(x + tok0 * 1024) + tid;
    char* lds = (char*)xt;
    for (int r = 0; r < 32; ++r) {
        float4 v = src[r * 256];
        uint2 p;
        p.x = f2bf(v.x) | (f2bf(v.y) << 16);
        p.y = f2bf(v.z) | (f2bf(v.w) << 16);
        *(uint2*)(lds + r * 2048 + ((tid * 8) ^ ((r & 7) << 4))) = p;
    }
    __syncthreads();

    {
        const int t = tid >> 3, kp = tid & 7;
        const float* wb = w + (size_t)b * 1024 + kp * 128;
        const char* pt = (const char*)xt + t * 2048;
        const int sw2 = (t & 7) << 4;
        float acc = 0.f;
#pragma unroll
        for (int j = 0; j < 16; ++j) {
            const int kb = (kp * 128 + j * 8) * 2;
            bf16x8 v = *(const bf16x8*)(pt + (kb ^ sw2));
#pragma unroll
            for (int e = 0; e < 8; ++e) acc += (float)v[e] * wb[j * 8 + e];
        }
        acc += __shfl_xor(acc, 1);
        acc += __shfl_xor(acc, 2);
        acc += __shfl_xor(acc, 4);
        if (kp == 0) numer[t] = acc;
    }
    __syncthreads();

    if (tid < 32) {
        float nt = nsq_g[tok0 + tid] + nsq_g[65536 + tok0 + tid];
        float s = numer[tid] / (EPS + sqrtf(nt));
        simv[tid] = s;
        sim_out[tok0 + tid] = s;
    }
    __syncthreads();

    {
        const int n0 = tid * 4;
        float a0 = 0.f, a1 = 0.f, a2 = 0.f, a3 = 0.f;
        const char* p = (const char*)xt;
#pragma unroll 4
        for (int t = 0; t < 32; ++t) {
            int byte = t * 2048 + ((n0 * 2) ^ ((t & 7) << 4));
            bf16x4 v = *(const bf16x4*)(p + byte);
            float s = simv[t];
            a0 += s * (float)v[0];
            a1 += s * (float)v[1];
            a2 += s * (float)v[2];
            a3 += s * (float)v[3];
        }
        float4 o; o.x = a0; o.y = a1; o.z = a2; o.w = a3;
        ((float4*)(outp + (size_t)bs * 1024))[tid] = o;
    }
}

// ---- out[b][j] = sum over NT tile partials ----
template <int NT>
__global__ void k_outred(const float* __restrict__ outp, float* __restrict__ out) {
    const int b = blockIdx.y, j = blockIdx.x * 256 + threadIdx.x;
    const float* p = outp + (size_t)b * NT * 1024 + j;
    float s = 0.f;
    for (int t = 0; t < NT; ++t) s += p[t * 1024];
    out[b * 1024 + j] = s;
}

extern "C" void kernel_launch(void* const* d_in, const int* in_sizes, int n_in,
                              void* d_out, int out_size, void* d_ws, size_t ws_size,
                              hipStream_t stream) {
    const float* x = (const float*)d_in[0];  // [16][4096][1024]
    const float* A = (const float*)d_in[1];  // [1024][1024]
    const float* B = (const float*)d_in[2];  // [1024][1024]
    float* out = (float*)d_out;              // [16][1024] then sim [16][4096]
    float* sim = out + 16 * 1024;
    float* ws = (float*)d_ws;
    float* xs_part = ws;                                  // 524288  (2 MB)
    float* q = ws + 540672;                               // 16384
    float* wv = ws + 557056;                              // 16384
    float* nsq = ws + 573440;                             // 131072 (fallback only)
    float* outp = ws + 704512;                            // up to 8 MB
    unsigned short* Bb = (unsigned short*)(ws + 2801664); // 1M bf16 (2 MB)
    unsigned short* xbf = (unsigned short*)(ws + 3325952);// 64M bf16 (128 MB, optional)
    const bool xb = ws_size >= (size_t)(3325952 + 33554432) * 4;

    if (xb) {
        k_prep<1><<<dim3(32, 16), 256, 0, stream>>>(x, xs_part, xbf);
        k_glue<<<1280, 256, 0, stream>>>(B, Bb, xs_part, A, q);
        k_wf<<<dim3(16, 16), 256, 0, stream>>>(B, q, wv);
        k_main2<<<256, 512, 0, stream>>>(xbf, Bb, wv, outp, sim);
        k_outred<16><<<dim3(4, 16), 256, 0, stream>>>(outp, out);
    } else {
        k_prep<0><<<dim3(32, 16), 256, 0, stream>>>(x, xs_part, (unsigned short*)0);
        k_glue<<<1280, 256, 0, stream>>>(B, Bb, xs_part, A, q);
        k_wf<<<dim3(16, 16), 256, 0, stream>>>(B, q, wv);
        k_nsq_f32<<<dim3(512, 2), 256, 0, stream>>>(x, Bb, nsq);
        k_finish0<<<2048, 256, 0, stream>>>(x, wv, nsq, outp, sim);
        k_outred<128><<<dim3(4, 16), 256, 0, stream>>>(outp, out);
    }
}